// Round 1
// baseline (833.511 us; speedup 1.0000x reference)
//
#include <hip/hip_runtime.h>
#include <math.h>

#define T_DIM 1000

// ---------------- Kernel 1: QKV GEMM + bias + PReLU + chanLN(512) ----------
// block = (b, t); 512 threads, thread = output channel o.
// Writes attention layout: hbuf[((b*8+head)*T + t)*512 + (o%64)*8 + f]
__global__ __launch_bounds__(512) void qkv_kernel(
    const float* __restrict__ x, const float* __restrict__ w,
    const float* __restrict__ bias, const float* __restrict__ a_p,
    const float* __restrict__ g, const float* __restrict__ be,
    float* __restrict__ hbuf) {
  int blk = blockIdx.x;
  int b = blk / T_DIM, t = blk % T_DIM;
  __shared__ float xs[2048];            // [c*8 + f]
  __shared__ float s1[8][8], s2[8][8];  // [f][wave]
  __shared__ float mu_s[8], ri_s[8];
  int tid = threadIdx.x;
#pragma unroll
  for (int i = 0; i < 4; ++i) {
    int e = tid + i * 512;
    int c = e >> 3, f = e & 7;
    xs[e] = x[((size_t)(b * 256 + c) * 8 + f) * T_DIM + t];
  }
  __syncthreads();
  int o = tid;
  float acc[8];
  float bo = bias[o];
#pragma unroll
  for (int f = 0; f < 8; ++f) acc[f] = bo;
  const float4* wrow = (const float4*)(w + (size_t)o * 256);
  for (int c4 = 0; c4 < 64; ++c4) {
    float4 wv = wrow[c4];
    const float* x0 = xs + c4 * 32;     // broadcast LDS reads (no conflicts)
#pragma unroll
    for (int f = 0; f < 8; ++f) {
      acc[f] += wv.x * x0[f] + wv.y * x0[8 + f] + wv.z * x0[16 + f] +
                wv.w * x0[24 + f];
    }
  }
  float a = a_p[0];
#pragma unroll
  for (int f = 0; f < 8; ++f) acc[f] = acc[f] >= 0.f ? acc[f] : a * acc[f];
  // LayerNorm over the 512 o-channels, separately per f
  int lane = tid & 63, wid = tid >> 6;
#pragma unroll
  for (int f = 0; f < 8; ++f) {
    float s = acc[f], q = acc[f] * acc[f];
    for (int off = 32; off > 0; off >>= 1) {
      s += __shfl_down(s, off, 64);
      q += __shfl_down(q, off, 64);
    }
    if (lane == 0) { s1[f][wid] = s; s2[f][wid] = q; }
  }
  __syncthreads();
  if (tid < 8) {
    float s = 0.f, q = 0.f;
    for (int j = 0; j < 8; ++j) { s += s1[tid][j]; q += s2[tid][j]; }
    float mu = s * (1.f / 512.f);
    float var = q * (1.f / 512.f) - mu * mu;
    mu_s[tid] = mu;
    ri_s[tid] = rsqrtf(var + 1e-5f);
  }
  __syncthreads();
  float go = g[o], beo = be[o];
  int head = o >> 6, lo = o & 63;
  float* dst = hbuf + ((size_t)(b * 8 + head) * T_DIM + t) * 512 + lo * 8;
#pragma unroll
  for (int f = 0; f < 8; ++f)
    dst[f] = (acc[f] - mu_s[f]) * ri_s[f] * go + beo;
}

// ---------------- Kernel 2: windowed causal attention ----------------------
// block = (b*8+h, t); 128 threads. q[0:128) k[128:256) v[256:512) per row.
__global__ __launch_bounds__(128) void attn_kernel(
    const float* __restrict__ hbuf, float* __restrict__ ctx) {
  int blk = blockIdx.x;
  int bh = blk / T_DIM, t = blk % T_DIM;
  const float* base = hbuf + (size_t)bh * T_DIM * 512;
  __shared__ float qs[128];
  __shared__ float ps[128];
  __shared__ float wm[2], wsum[2];
  int tid = threadIdx.x;
  qs[tid] = base[(size_t)t * 512 + tid];
  __syncthreads();
  int s0 = t > 100 ? t - 100 : 0;
  int ns = t - s0 + 1;  // 1..101 keys
  float sc = -INFINITY;
  if (tid < ns) {
    const float4* k4 = (const float4*)(base + (size_t)(s0 + tid) * 512 + 128);
    const float4* q4 = (const float4*)qs;
    float d = 0.f;
#pragma unroll 8
    for (int i = 0; i < 32; ++i) {
      float4 kk = k4[i];
      float4 qq = q4[i];
      d += qq.x * kk.x + qq.y * kk.y + qq.z * kk.z + qq.w * kk.w;
    }
    sc = d * 0.08838834764831843f;  // 1/sqrt(128)
  }
  int lane = tid & 63, wid = tid >> 6;
  float m = sc;
  for (int off = 32; off > 0; off >>= 1) m = fmaxf(m, __shfl_down(m, off, 64));
  if (lane == 0) wm[wid] = m;
  __syncthreads();
  float gm = fmaxf(wm[0], wm[1]);
  float e = (tid < ns) ? __expf(sc - gm) : 0.f;
  float s = e;
  for (int off = 32; off > 0; off >>= 1) s += __shfl_down(s, off, 64);
  if (lane == 0) wsum[wid] = s;
  __syncthreads();
  float inv = 1.f / (wsum[0] + wsum[1]);
  ps[tid] = e * inv;
  __syncthreads();
  float acc0 = 0.f, acc1 = 0.f;
  for (int si = 0; si < ns; ++si) {
    float p = ps[si];
    const float* vrow = base + (size_t)(s0 + si) * 512 + 256;
    acc0 += p * vrow[tid];          // lane-coalesced
    acc1 += p * vrow[tid + 128];
  }
  float* crow = ctx + (size_t)blk * 256;
  crow[tid] = acc0;
  crow[tid + 128] = acc1;
}

// ---------------- Kernel 3: proj GEMM + bias + PReLU + chanLN(256) ---------
// block = (b, t); 256 threads, thread = output channel o. Output (B,C,F,T).
__global__ __launch_bounds__(256) void proj_kernel(
    const float* __restrict__ ctx, const float* __restrict__ w,
    const float* __restrict__ bias, const float* __restrict__ a_p,
    const float* __restrict__ g, const float* __restrict__ be,
    float* __restrict__ out) {
  int blk = blockIdx.x;
  int b = blk / T_DIM, t = blk % T_DIM;
  __shared__ float cs[2048];            // [c*8 + f], c = h*32+vh
  __shared__ float s1[8][4], s2[8][4];
  __shared__ float mu_s[8], ri_s[8];
  int tid = threadIdx.x;
#pragma unroll
  for (int i = 0; i < 8; ++i)
    cs[i * 256 + tid] = ctx[((size_t)(b * 8 + i) * T_DIM + t) * 256 + tid];
  __syncthreads();
  int o = tid;
  float acc[8];
  float bo = bias[o];
#pragma unroll
  for (int f = 0; f < 8; ++f) acc[f] = bo;
  const float4* wrow = (const float4*)(w + (size_t)o * 256);
  for (int c4 = 0; c4 < 64; ++c4) {
    float4 wv = wrow[c4];
    const float* x0 = cs + c4 * 32;
#pragma unroll
    for (int f = 0; f < 8; ++f) {
      acc[f] += wv.x * x0[f] + wv.y * x0[8 + f] + wv.z * x0[16 + f] +
                wv.w * x0[24 + f];
    }
  }
  float a = a_p[0];
#pragma unroll
  for (int f = 0; f < 8; ++f) acc[f] = acc[f] >= 0.f ? acc[f] : a * acc[f];
  int lane = tid & 63, wid = tid >> 6;
#pragma unroll
  for (int f = 0; f < 8; ++f) {
    float s = acc[f], q = acc[f] * acc[f];
    for (int off = 32; off > 0; off >>= 1) {
      s += __shfl_down(s, off, 64);
      q += __shfl_down(q, off, 64);
    }
    if (lane == 0) { s1[f][wid] = s; s2[f][wid] = q; }
  }
  __syncthreads();
  if (tid < 8) {
    float s = 0.f, q = 0.f;
    for (int j = 0; j < 4; ++j) { s += s1[tid][j]; q += s2[tid][j]; }
    float mu = s * (1.f / 256.f);
    float var = q * (1.f / 256.f) - mu * mu;
    mu_s[tid] = mu;
    ri_s[tid] = rsqrtf(var + 1e-5f);
  }
  __syncthreads();
  float go = g[o], beo = be[o];
#pragma unroll
  for (int f = 0; f < 8; ++f)
    out[((size_t)(b * 256 + o) * 8 + f) * T_DIM + t] =
        (acc[f] - mu_s[f]) * ri_s[f] * go + beo;
}

extern "C" void kernel_launch(void* const* d_in, const int* in_sizes, int n_in,
                              void* d_out, int out_size, void* d_ws,
                              size_t ws_size, hipStream_t stream) {
  const float* x = (const float*)d_in[0];
  const float* w_qkv = (const float*)d_in[1];
  const float* b_qkv = (const float*)d_in[2];
  const float* a_qkv = (const float*)d_in[3];
  const float* g_qkv = (const float*)d_in[4];
  const float* be_qkv = (const float*)d_in[5];
  const float* w_proj = (const float*)d_in[6];
  const float* b_proj = (const float*)d_in[7];
  const float* a_proj = (const float*)d_in[8];
  const float* g_proj = (const float*)d_in[9];
  const float* be_proj = (const float*)d_in[10];
  float* out = (float*)d_out;

  float* hbuf = (float*)d_ws;                          // 4*8*1000*512 floats
  float* ctx = hbuf + (size_t)4 * 8 * T_DIM * 512;     // 4*8*1000*256 floats

  qkv_kernel<<<4 * T_DIM, 512, 0, stream>>>(x, w_qkv, b_qkv, a_qkv, g_qkv,
                                            be_qkv, hbuf);
  attn_kernel<<<4 * 8 * T_DIM, 128, 0, stream>>>(hbuf, ctx);
  proj_kernel<<<4 * T_DIM, 256, 0, stream>>>(ctx, w_proj, b_proj, a_proj,
                                             g_proj, be_proj, out);
}

// Round 2
// 786.441 us; speedup vs baseline: 1.0599x; 1.0599x over previous
//
#include <hip/hip_runtime.h>
#include <math.h>

#define T_DIM 1000
#define B_DIM 4

// ---------- generic batched 64x64 tiled transpose: in[b][R][C] -> out[b][C][R]
__global__ __launch_bounds__(256) void transpose_k(const float* __restrict__ in,
                                                   float* __restrict__ out,
                                                   int R, int C) {
  __shared__ float tile[64][65];
  size_t bb = (size_t)blockIdx.z * R * C;
  const float* inb = in + bb;
  float* outb = out + bb;
  int c0 = blockIdx.x * 64, r0 = blockIdx.y * 64;
  int tc = threadIdx.x & 63, tg = threadIdx.x >> 6;  // tg 0..3
  int cc = c0 + tc;
  if (cc < C) {
#pragma unroll
    for (int i = 0; i < 16; ++i) {
      int r = i * 4 + tg;
      int rr = r0 + r;
      if (rr < R) tile[r][tc] = inb[(size_t)rr * C + cc];
    }
  }
  __syncthreads();
  int rr = r0 + tc;
  if (rr < R) {
#pragma unroll
    for (int i = 0; i < 16; ++i) {
      int c = i * 4 + tg;
      if (c0 + c < C) outb[(size_t)(c0 + c) * R + rr] = tile[tc][c];
    }
  }
}

// ---------- Kernel 1: QKV GEMM + bias + PReLU + chanLN(512) ----------------
// block = (b, t-tile of 4); 512 threads. subgroup ts=tid>>7 owns t0+ts;
// lane-in-group l=tid&127 owns o = 4l..4l+3. Reads xt[b][t][cf] coalesced.
__global__ __launch_bounds__(512) void qkv_kernel(
    const float* __restrict__ xt, const float* __restrict__ w,
    const float* __restrict__ bias, const float* __restrict__ a_p,
    const float* __restrict__ gam, const float* __restrict__ be,
    float* __restrict__ hbuf) {
  int blk = blockIdx.x;
  int b = blk / 250, t0 = (blk % 250) * 4;
  __shared__ float xs[4][2048];
  __shared__ float redS[4][2][8], redQ[4][2][8];
  __shared__ float mu_s[4][8], ri_s[4][8];
  int tid = threadIdx.x;
  {
    const float4* src = (const float4*)(xt + ((size_t)b * T_DIM + t0) * 2048);
    float4* dst4 = (float4*)xs;
#pragma unroll
    for (int i = 0; i < 4; ++i) dst4[tid + i * 512] = src[tid + i * 512];
  }
  __syncthreads();
  int ts = tid >> 7, l = tid & 127;
  int o0 = l * 4;
  const float* xrow = xs[ts];
  float acc[4][8];
#pragma unroll
  for (int oo = 0; oo < 4; ++oo) {
    float bo = bias[o0 + oo];
#pragma unroll
    for (int f = 0; f < 8; ++f) acc[oo][f] = bo;
  }
  const float4* w4 = (const float4*)w;  // w[o][c] row-major, 64 float4/row
  for (int c4 = 0; c4 < 64; ++c4) {
    float4 wq[4];
#pragma unroll
    for (int oo = 0; oo < 4; ++oo) wq[oo] = w4[(size_t)(o0 + oo) * 64 + c4];
    float4 xa[8];
    const float4* x4 = (const float4*)(xrow + c4 * 32);
#pragma unroll
    for (int j = 0; j < 8; ++j) xa[j] = x4[j];
    const float* xr = (const float*)xa;  // xr[cc*8+f]
#pragma unroll
    for (int oo = 0; oo < 4; ++oo) {
#pragma unroll
      for (int f = 0; f < 8; ++f) {
        acc[oo][f] += wq[oo].x * xr[f] + wq[oo].y * xr[8 + f] +
                      wq[oo].z * xr[16 + f] + wq[oo].w * xr[24 + f];
      }
    }
  }
  float a = a_p[0];
#pragma unroll
  for (int oo = 0; oo < 4; ++oo)
#pragma unroll
    for (int f = 0; f < 8; ++f)
      acc[oo][f] = acc[oo][f] >= 0.f ? acc[oo][f] : a * acc[oo][f];
  // LN over 512 o per (t, f): reduce over the 128-thread subgroup (2 waves)
  int wv = (tid >> 6) & 1, lane = tid & 63;
#pragma unroll
  for (int f = 0; f < 8; ++f) {
    float s = acc[0][f] + acc[1][f] + acc[2][f] + acc[3][f];
    float q = acc[0][f] * acc[0][f] + acc[1][f] * acc[1][f] +
              acc[2][f] * acc[2][f] + acc[3][f] * acc[3][f];
    for (int off = 32; off > 0; off >>= 1) {
      s += __shfl_down(s, off, 64);
      q += __shfl_down(q, off, 64);
    }
    if (lane == 0) { redS[ts][wv][f] = s; redQ[ts][wv][f] = q; }
  }
  __syncthreads();
  if (tid < 32) {
    int t2 = tid >> 3, f2 = tid & 7;
    float s = redS[t2][0][f2] + redS[t2][1][f2];
    float q = redQ[t2][0][f2] + redQ[t2][1][f2];
    float mu = s * (1.f / 512.f);
    float var = q * (1.f / 512.f) - mu * mu;
    mu_s[t2][f2] = mu;
    ri_s[t2][f2] = rsqrtf(var + 1e-5f);
  }
  __syncthreads();
#pragma unroll
  for (int oo = 0; oo < 4; ++oo) {
    int o = o0 + oo;
    float go = gam[o], beo = be[o];
    int head = o >> 6, lo = o & 63;
    float* dst =
        hbuf + ((size_t)(b * 8 + head) * T_DIM + (t0 + ts)) * 512 + lo * 8;
    float4 v0, v1;
    v0.x = (acc[oo][0] - mu_s[ts][0]) * ri_s[ts][0] * go + beo;
    v0.y = (acc[oo][1] - mu_s[ts][1]) * ri_s[ts][1] * go + beo;
    v0.z = (acc[oo][2] - mu_s[ts][2]) * ri_s[ts][2] * go + beo;
    v0.w = (acc[oo][3] - mu_s[ts][3]) * ri_s[ts][3] * go + beo;
    v1.x = (acc[oo][4] - mu_s[ts][4]) * ri_s[ts][4] * go + beo;
    v1.y = (acc[oo][5] - mu_s[ts][5]) * ri_s[ts][5] * go + beo;
    v1.z = (acc[oo][6] - mu_s[ts][6]) * ri_s[ts][6] * go + beo;
    v1.w = (acc[oo][7] - mu_s[ts][7]) * ri_s[ts][7] * go + beo;
    ((float4*)dst)[0] = v0;
    ((float4*)dst)[1] = v1;
  }
}

// ---------- Kernel 2: windowed causal attention, 8 queries / block ---------
// grid (125, 32), 128 threads. hbuf row: q[0:128) k[128:256) v[256:512).
__global__ __launch_bounds__(128) void attn_kernel(
    const float* __restrict__ hbuf, float* __restrict__ ctx) {
  int bh = blockIdx.y;
  int t0 = blockIdx.x * 8;
  const float* base = hbuf + (size_t)bh * T_DIM * 512;
  __shared__ float qs[8][128];
  __shared__ float ps[8][136];
  int tid = threadIdx.x;
#pragma unroll
  for (int i = 0; i < 8; ++i) qs[i][tid] = base[(size_t)(t0 + i) * 512 + tid];
  int s0 = t0 > 100 ? t0 - 100 : 0;
  int ns = t0 + 8 - s0;  // <= 108
  __syncthreads();
  float scq[8];
  int si = tid;
  if (si < ns) {
    int s = s0 + si;
    const float4* k4 = (const float4*)(base + (size_t)s * 512 + 128);
    float d[8];
#pragma unroll
    for (int q = 0; q < 8; ++q) d[q] = 0.f;
    for (int i = 0; i < 32; ++i) {
      float4 kk = k4[i];
#pragma unroll
      for (int q = 0; q < 8; ++q) {
        float4 qq = ((const float4*)qs[q])[i];
        d[q] += qq.x * kk.x + qq.y * kk.y + qq.z * kk.z + qq.w * kk.w;
      }
    }
    int ds = s - t0;
#pragma unroll
    for (int q = 0; q < 8; ++q)
      scq[q] = (ds <= q && ds >= q - 100) ? d[q] * 0.08838834764831843f
                                          : -INFINITY;
  } else {
#pragma unroll
    for (int q = 0; q < 8; ++q) scq[q] = -INFINITY;
  }
#pragma unroll
  for (int q = 0; q < 8; ++q) ps[q][tid] = scq[q];
  __syncthreads();
  int wv = tid >> 6, lane = tid & 63;
#pragma unroll
  for (int qq = 0; qq < 4; ++qq) {
    int q = wv * 4 + qq;
    float v0 = ps[q][lane], v1 = ps[q][lane + 64];
    float m = fmaxf(v0, v1);
    for (int off = 32; off > 0; off >>= 1)
      m = fmaxf(m, __shfl_xor(m, off, 64));
    float e0 = __expf(v0 - m), e1 = __expf(v1 - m);
    float sm = e0 + e1;
    for (int off = 32; off > 0; off >>= 1) sm += __shfl_xor(sm, off, 64);
    float inv = 1.f / sm;
    ps[q][lane] = e0 * inv;
    ps[q][lane + 64] = e1 * inv;
  }
  __syncthreads();
  float a0[8], a1[8];
#pragma unroll
  for (int q = 0; q < 8; ++q) { a0[q] = 0.f; a1[q] = 0.f; }
  for (int si2 = 0; si2 < ns; ++si2) {
    const float* vrow = base + (size_t)(s0 + si2) * 512 + 256;
    float v0 = vrow[tid], v1 = vrow[tid + 128];
#pragma unroll
    for (int q = 0; q < 8; ++q) {
      float p = ps[q][si2];
      a0[q] += p * v0;
      a1[q] += p * v1;
    }
  }
#pragma unroll
  for (int q = 0; q < 8; ++q) {
    float* crow = ctx + ((size_t)bh * T_DIM + t0 + q) * 256;
    crow[tid] = a0[q];
    crow[tid + 128] = a1[q];
  }
}

// ---------- Kernel 3: proj GEMM + bias + PReLU + chanLN(256) ---------------
// block = (b, t); 256 threads, thread = o. Writes coalesced tmp[b][t][o*8+f].
__global__ __launch_bounds__(256) void proj_kernel(
    const float* __restrict__ ctx, const float* __restrict__ w,
    const float* __restrict__ bias, const float* __restrict__ a_p,
    const float* __restrict__ gam, const float* __restrict__ be,
    float* __restrict__ tmp) {
  int blk = blockIdx.x;
  int b = blk / T_DIM, t = blk % T_DIM;
  __shared__ float cs[2048];
  __shared__ float s1[8][4], s2[8][4];
  __shared__ float mu_s[8], ri_s[8];
  int tid = threadIdx.x;
#pragma unroll
  for (int i = 0; i < 8; ++i)
    cs[i * 256 + tid] = ctx[((size_t)(b * 8 + i) * T_DIM + t) * 256 + tid];
  __syncthreads();
  int o = tid;
  float acc[8];
  float bo = bias[o];
#pragma unroll
  for (int f = 0; f < 8; ++f) acc[f] = bo;
  const float4* wrow = (const float4*)(w + (size_t)o * 256);
  for (int c4 = 0; c4 < 64; ++c4) {
    float4 wv = wrow[c4];
    const float* x0 = cs + c4 * 32;
#pragma unroll
    for (int f = 0; f < 8; ++f) {
      acc[f] += wv.x * x0[f] + wv.y * x0[8 + f] + wv.z * x0[16 + f] +
                wv.w * x0[24 + f];
    }
  }
  float a = a_p[0];
#pragma unroll
  for (int f = 0; f < 8; ++f) acc[f] = acc[f] >= 0.f ? acc[f] : a * acc[f];
  int lane = tid & 63, wid = tid >> 6;
#pragma unroll
  for (int f = 0; f < 8; ++f) {
    float s = acc[f], q = acc[f] * acc[f];
    for (int off = 32; off > 0; off >>= 1) {
      s += __shfl_down(s, off, 64);
      q += __shfl_down(q, off, 64);
    }
    if (lane == 0) { s1[f][wid] = s; s2[f][wid] = q; }
  }
  __syncthreads();
  if (tid < 8) {
    float s = 0.f, q = 0.f;
    for (int j = 0; j < 4; ++j) { s += s1[tid][j]; q += s2[tid][j]; }
    float mu = s * (1.f / 256.f);
    float var = q * (1.f / 256.f) - mu * mu;
    mu_s[tid] = mu;
    ri_s[tid] = rsqrtf(var + 1e-5f);
  }
  __syncthreads();
  float go = gam[o], beo = be[o];
  float* dst = tmp + ((size_t)b * T_DIM + t) * 2048 + o * 8;
  float4 v0, v1;
  v0.x = (acc[0] - mu_s[0]) * ri_s[0] * go + beo;
  v0.y = (acc[1] - mu_s[1]) * ri_s[1] * go + beo;
  v0.z = (acc[2] - mu_s[2]) * ri_s[2] * go + beo;
  v0.w = (acc[3] - mu_s[3]) * ri_s[3] * go + beo;
  v1.x = (acc[4] - mu_s[4]) * ri_s[4] * go + beo;
  v1.y = (acc[5] - mu_s[5]) * ri_s[5] * go + beo;
  v1.z = (acc[6] - mu_s[6]) * ri_s[6] * go + beo;
  v1.w = (acc[7] - mu_s[7]) * ri_s[7] * go + beo;
  ((float4*)dst)[0] = v0;
  ((float4*)dst)[1] = v1;
}

extern "C" void kernel_launch(void* const* d_in, const int* in_sizes, int n_in,
                              void* d_out, int out_size, void* d_ws,
                              size_t ws_size, hipStream_t stream) {
  const float* x = (const float*)d_in[0];
  const float* w_qkv = (const float*)d_in[1];
  const float* b_qkv = (const float*)d_in[2];
  const float* a_qkv = (const float*)d_in[3];
  const float* g_qkv = (const float*)d_in[4];
  const float* be_qkv = (const float*)d_in[5];
  const float* w_proj = (const float*)d_in[6];
  const float* b_proj = (const float*)d_in[7];
  const float* a_proj = (const float*)d_in[8];
  const float* g_proj = (const float*)d_in[9];
  const float* be_proj = (const float*)d_in[10];
  float* out = (float*)d_out;

  float* xt = (float*)d_ws;                            // 4*1000*2048
  float* hbuf = xt + (size_t)B_DIM * T_DIM * 2048;     // 4*8*1000*512
  float* ctx = hbuf + (size_t)B_DIM * 8 * T_DIM * 512; // 4*8*1000*256
  float* tmp = hbuf;  // reuse: hbuf dead after attn

  // x (B,2048,T) -> xt (B,T,2048)
  transpose_k<<<dim3(16, 32, B_DIM), 256, 0, stream>>>(x, xt, 2048, T_DIM);
  qkv_kernel<<<B_DIM * 250, 512, 0, stream>>>(xt, w_qkv, b_qkv, a_qkv, g_qkv,
                                              be_qkv, hbuf);
  attn_kernel<<<dim3(125, 32), 128, 0, stream>>>(hbuf, ctx);
  proj_kernel<<<B_DIM * T_DIM, 256, 0, stream>>>(ctx, w_proj, b_proj, a_proj,
                                                 g_proj, be_proj, tmp);
  // tmp (B,T,2048) -> out (B,2048,T)
  transpose_k<<<dim3(32, 16, B_DIM), 256, 0, stream>>>(tmp, out, T_DIM, 2048);
}

// Round 3
// 285.208 us; speedup vs baseline: 2.9225x; 2.7574x over previous
//
#include <hip/hip_runtime.h>
#include <math.h>

#define T_DIM 1000

typedef __attribute__((ext_vector_type(8))) short short8;
typedef __attribute__((ext_vector_type(16))) float f32x16;

static __device__ __forceinline__ short bf16_rn(float f) {
  union { float f; unsigned u; } v;
  v.f = f;
  unsigned r = v.u + 0x7fffu + ((v.u >> 16) & 1u);
  return (short)(r >> 16);
}

__global__ __launch_bounds__(256) void cvt_bf16(const float* __restrict__ in,
                                                short* __restrict__ out,
                                                int n) {
  int i = blockIdx.x * 256 + threadIdx.x;
  if (i < n) out[i] = bf16_rn(in[i]);
}

// x[b][c][f][t] fp32 -> xbt[(b*T+t)*8+f][256] bf16
__global__ __launch_bounds__(256) void xpose_x(const float* __restrict__ x,
                                               short* __restrict__ xbt) {
  __shared__ float tile[64][65];
  int bf = blockIdx.z;  // b*8+f
  int b = bf >> 3, f = bf & 7;
  int c0 = blockIdx.x * 64, t0 = blockIdx.y * 64;
  int tid = threadIdx.x;
  int tc = tid & 63, tg = tid >> 2;
  int t = t0 + tc;
  if (t < T_DIM) {
    int sg = tid >> 6;  // 0..3
#pragma unroll
    for (int i = 0; i < 16; ++i) {
      int cr = i * 4 + sg;
      tile[cr][tc] = x[((size_t)(b * 256 + c0 + cr) * 8 + f) * T_DIM + t];
    }
  }
  __syncthreads();
  int tr = tid >> 2, cg = (tid & 3) * 16;
  int tt = t0 + tr;
  (void)tg;
  if (tt < T_DIM) {
    short tmp[16];
#pragma unroll
    for (int i = 0; i < 16; ++i) tmp[i] = bf16_rn(tile[cg + i][tr]);
    short* dst = xbt + ((size_t)((b * T_DIM + tt) * 8 + f)) * 256 + c0 + cg;
    *(short8*)dst = *(short8*)tmp;
    *(short8*)(dst + 8) = *(short8*)(tmp + 8);
  }
}

// ---------------- QKV: MFMA GEMM M=512 K=256 Ntile=32 + bias/PReLU/LN ------
__global__ __launch_bounds__(256) void qkv_mfma(
    const short* __restrict__ xbt, const short* __restrict__ wb,
    const float* __restrict__ bias, const float* __restrict__ a_p,
    const float* __restrict__ gam, const float* __restrict__ bet,
    float* __restrict__ hbuf) {
  __shared__ short Bs[32][264];  // pitch 264 bf16 = 132 words -> conflict-free
  __shared__ float lnS[4][32], lnQ[4][32];
  __shared__ float mu_s[32], ri_s[32];
  __shared__ float pb[512], pg[512], pe[512];
  int tid = threadIdx.x;
  int blk = blockIdx.x;
  int n0 = blk * 32;
  int b = blk / 250;
  for (int i = tid; i < 512; i += 256) {
    pb[i] = bias[i];
    pg[i] = gam[i];
    pe[i] = bet[i];
  }
  {
    int n = tid >> 3, ch = tid & 7;
    const short8* src =
        (const short8*)(xbt + ((size_t)(n0 + n)) * 256 + ch * 32);
#pragma unroll
    for (int j = 0; j < 4; ++j) *(short8*)&Bs[n][ch * 32 + 8 * j] = src[j];
  }
  __syncthreads();
  int lane = tid & 63, wv = tid >> 6;
  int half = lane >> 5, ln32 = lane & 31;
  int m0 = wv * 128;
  f32x16 acc[4];
#pragma unroll
  for (int mt = 0; mt < 4; ++mt)
#pragma unroll
    for (int r = 0; r < 16; ++r) acc[mt][r] = 0.f;
  const short* wbase = wb + ((size_t)(m0 + ln32)) * 256 + half * 8;
#pragma unroll
  for (int kk = 0; kk < 16; ++kk) {
    int k0 = kk * 16;
    short8 bfrag = *(const short8*)&Bs[ln32][k0 + half * 8];
#pragma unroll
    for (int mt = 0; mt < 4; ++mt) {
      short8 afrag = *(const short8*)(wbase + (size_t)mt * 32 * 256 + k0);
      acc[mt] =
          __builtin_amdgcn_mfma_f32_32x32x16_bf16(afrag, bfrag, acc[mt], 0, 0, 0);
    }
  }
  float aslope = a_p[0];
  float s = 0.f, q = 0.f;
#pragma unroll
  for (int mt = 0; mt < 4; ++mt) {
#pragma unroll
    for (int r = 0; r < 16; ++r) {
      int row = (r & 3) + 8 * (r >> 2) + 4 * half;
      int o = m0 + mt * 32 + row;
      float v = acc[mt][r] + pb[o];
      v = v >= 0.f ? v : aslope * v;
      acc[mt][r] = v;
      s += v;
      q += v * v;
    }
  }
  s += __shfl_xor(s, 32, 64);
  q += __shfl_xor(q, 32, 64);
  if (half == 0) {
    lnS[wv][ln32] = s;
    lnQ[wv][ln32] = q;
  }
  __syncthreads();
  if (tid < 32) {
    float ss = lnS[0][tid] + lnS[1][tid] + lnS[2][tid] + lnS[3][tid];
    float qq = lnQ[0][tid] + lnQ[1][tid] + lnQ[2][tid] + lnQ[3][tid];
    float mu = ss * (1.f / 512.f);
    float var = qq * (1.f / 512.f) - mu * mu;
    mu_s[tid] = mu;
    ri_s[tid] = rsqrtf(var + 1e-5f);
  }
  __syncthreads();
  float mu = mu_s[ln32], ri = ri_s[ln32];
  int n = n0 + ln32;
  int f = n & 7;
  int tg = (n >> 3) - b * T_DIM;
#pragma unroll
  for (int mt = 0; mt < 4; ++mt) {
#pragma unroll
    for (int r = 0; r < 16; ++r) {
      int row = (r & 3) + 8 * (r >> 2) + 4 * half;
      int o = m0 + mt * 32 + row;
      float v = (acc[mt][r] - mu) * ri * pg[o] + pe[o];
      int head = o >> 6, lo = o & 63;
      hbuf[((size_t)(b * 8 + head) * T_DIM + tg) * 512 + lo * 8 + f] = v;
    }
  }
}

// ---------------- attention: 8 queries/block, fp32 ----------------
// writes ctxf[((b*8+f)*T + t)*256 + h*32 + vh]
__global__ __launch_bounds__(128) void attn_kernel(
    const float* __restrict__ hbuf, float* __restrict__ ctxf) {
  int bh = blockIdx.y;
  int t0 = blockIdx.x * 8;
  const float* base = hbuf + (size_t)bh * T_DIM * 512;
  __shared__ float qs[8][128];
  __shared__ float ps[8][136];
  __shared__ float sctx[8][264];
  int tid = threadIdx.x;
#pragma unroll
  for (int i = 0; i < 8; ++i) qs[i][tid] = base[(size_t)(t0 + i) * 512 + tid];
  int s0 = t0 > 100 ? t0 - 100 : 0;
  int ns = t0 + 8 - s0;  // <= 108
  __syncthreads();
  float scq[8];
  int si = tid;
  if (si < ns) {
    int s = s0 + si;
    const float4* k4 = (const float4*)(base + (size_t)s * 512 + 128);
    float d[8];
#pragma unroll
    for (int q = 0; q < 8; ++q) d[q] = 0.f;
    for (int i = 0; i < 32; ++i) {
      float4 kk = k4[i];
#pragma unroll
      for (int q = 0; q < 8; ++q) {
        float4 qq = ((const float4*)qs[q])[i];
        d[q] += qq.x * kk.x + qq.y * kk.y + qq.z * kk.z + qq.w * kk.w;
      }
    }
    int ds = s - t0;
#pragma unroll
    for (int q = 0; q < 8; ++q)
      scq[q] = (ds <= q && ds >= q - 100) ? d[q] * 0.08838834764831843f
                                          : -INFINITY;
  } else {
#pragma unroll
    for (int q = 0; q < 8; ++q) scq[q] = -INFINITY;
  }
#pragma unroll
  for (int q = 0; q < 8; ++q) ps[q][tid] = scq[q];
  __syncthreads();
  int wv = tid >> 6, lane = tid & 63;
#pragma unroll
  for (int qq = 0; qq < 4; ++qq) {
    int q = wv * 4 + qq;
    float v0 = ps[q][lane], v1 = ps[q][lane + 64];
    float m = fmaxf(v0, v1);
    for (int off = 32; off > 0; off >>= 1) m = fmaxf(m, __shfl_xor(m, off, 64));
    float e0 = __expf(v0 - m), e1 = __expf(v1 - m);
    float sm = e0 + e1;
    for (int off = 32; off > 0; off >>= 1) sm += __shfl_xor(sm, off, 64);
    float inv = 1.f / sm;
    ps[q][lane] = e0 * inv;
    ps[q][lane + 64] = e1 * inv;
  }
  __syncthreads();
  float a0[8], a1[8];
#pragma unroll
  for (int q = 0; q < 8; ++q) {
    a0[q] = 0.f;
    a1[q] = 0.f;
  }
  for (int si2 = 0; si2 < ns; ++si2) {
    const float* vrow = base + (size_t)(s0 + si2) * 512 + 256;
    float v0 = vrow[tid], v1 = vrow[tid + 128];
#pragma unroll
    for (int q = 0; q < 8; ++q) {
      float p = ps[q][si2];
      a0[q] += p * v0;
      a1[q] += p * v1;
    }
  }
#pragma unroll
  for (int q = 0; q < 8; ++q) {
    sctx[q][tid] = a0[q];
    sctx[q][tid + 128] = a1[q];
  }
  __syncthreads();
  int b = bh >> 3, h = bh & 7;
  int chunk = tid >> 1, hf = tid & 1;
  int qq = chunk >> 3, ff = chunk & 7, vh0 = hf * 16;
  float* dst =
      ctxf + ((size_t)((b * 8 + ff) * T_DIM) + t0 + qq) * 256 + h * 32 + vh0;
#pragma unroll
  for (int j = 0; j < 4; ++j) {
    float4 v;
    v.x = sctx[qq][(vh0 + 4 * j + 0) * 8 + ff];
    v.y = sctx[qq][(vh0 + 4 * j + 1) * 8 + ff];
    v.z = sctx[qq][(vh0 + 4 * j + 2) * 8 + ff];
    v.w = sctx[qq][(vh0 + 4 * j + 3) * 8 + ff];
    ((float4*)dst)[j] = v;
  }
}

// ---------------- proj: MFMA GEMM M=256 K=256 Ntile=32 + bias/PReLU/LN -----
// columns n = t0..t0+31 at fixed (b,f); writes out[(b*2048+o*8+f)*T + t]
__global__ __launch_bounds__(256) void proj_mfma(
    const float* __restrict__ ctxf, const short* __restrict__ wb,
    const float* __restrict__ bias, const float* __restrict__ a_p,
    const float* __restrict__ gam, const float* __restrict__ bet,
    float* __restrict__ out) {
  __shared__ short Bs[32][264];
  __shared__ float lnS[4][32], lnQ[4][32];
  __shared__ float mu_s[32], ri_s[32];
  __shared__ float pb[256], pg[256], pe[256];
  int tid = threadIdx.x;
  int blk = blockIdx.x;
  int bf = blk >> 5, tb = blk & 31;
  int b = bf >> 3, f = bf & 7;
  int t0 = tb * 32;
  pb[tid] = bias[tid];
  pg[tid] = gam[tid];
  pe[tid] = bet[tid];
  {
    int n = tid >> 3, ch = tid & 7;
    int t = t0 + n;
    short tmp[32];
    if (t < T_DIM) {
      const float4* src =
          (const float4*)(ctxf + ((size_t)bf * T_DIM + t) * 256 + ch * 32);
#pragma unroll
      for (int j = 0; j < 8; ++j) {
        float4 v = src[j];
        tmp[4 * j + 0] = bf16_rn(v.x);
        tmp[4 * j + 1] = bf16_rn(v.y);
        tmp[4 * j + 2] = bf16_rn(v.z);
        tmp[4 * j + 3] = bf16_rn(v.w);
      }
    } else {
#pragma unroll
      for (int j = 0; j < 32; ++j) tmp[j] = 0;
    }
#pragma unroll
    for (int j = 0; j < 4; ++j)
      *(short8*)&Bs[n][ch * 32 + 8 * j] = *(short8*)&tmp[8 * j];
  }
  __syncthreads();
  int lane = tid & 63, wv = tid >> 6;
  int half = lane >> 5, ln32 = lane & 31;
  int m0 = wv * 64;
  f32x16 acc[2];
#pragma unroll
  for (int mt = 0; mt < 2; ++mt)
#pragma unroll
    for (int r = 0; r < 16; ++r) acc[mt][r] = 0.f;
  const short* wbase = wb + ((size_t)(m0 + ln32)) * 256 + half * 8;
#pragma unroll
  for (int kk = 0; kk < 16; ++kk) {
    int k0 = kk * 16;
    short8 bfrag = *(const short8*)&Bs[ln32][k0 + half * 8];
#pragma unroll
    for (int mt = 0; mt < 2; ++mt) {
      short8 afrag = *(const short8*)(wbase + (size_t)mt * 32 * 256 + k0);
      acc[mt] =
          __builtin_amdgcn_mfma_f32_32x32x16_bf16(afrag, bfrag, acc[mt], 0, 0, 0);
    }
  }
  float aslope = a_p[0];
  float s = 0.f, q = 0.f;
#pragma unroll
  for (int mt = 0; mt < 2; ++mt) {
#pragma unroll
    for (int r = 0; r < 16; ++r) {
      int row = (r & 3) + 8 * (r >> 2) + 4 * half;
      int o = m0 + mt * 32 + row;
      float v = acc[mt][r] + pb[o];
      v = v >= 0.f ? v : aslope * v;
      acc[mt][r] = v;
      s += v;
      q += v * v;
    }
  }
  s += __shfl_xor(s, 32, 64);
  q += __shfl_xor(q, 32, 64);
  if (half == 0) {
    lnS[wv][ln32] = s;
    lnQ[wv][ln32] = q;
  }
  __syncthreads();
  if (tid < 32) {
    float ss = lnS[0][tid] + lnS[1][tid] + lnS[2][tid] + lnS[3][tid];
    float qq = lnQ[0][tid] + lnQ[1][tid] + lnQ[2][tid] + lnQ[3][tid];
    float mu = ss * (1.f / 256.f);
    float var = qq * (1.f / 256.f) - mu * mu;
    mu_s[tid] = mu;
    ri_s[tid] = rsqrtf(var + 1e-5f);
  }
  __syncthreads();
  float mu = mu_s[ln32], ri = ri_s[ln32];
  int t = t0 + ln32;
  if (t < T_DIM) {
#pragma unroll
    for (int mt = 0; mt < 2; ++mt) {
#pragma unroll
      for (int r = 0; r < 16; ++r) {
        int row = (r & 3) + 8 * (r >> 2) + 4 * half;
        int o = m0 + mt * 32 + row;
        float v = (acc[mt][r] - mu) * ri * pg[o] + pe[o];
        out[((size_t)(b * 2048 + o * 8 + f)) * T_DIM + t] = v;
      }
    }
  }
}

extern "C" void kernel_launch(void* const* d_in, const int* in_sizes, int n_in,
                              void* d_out, int out_size, void* d_ws,
                              size_t ws_size, hipStream_t stream) {
  const float* x = (const float*)d_in[0];
  const float* w_qkv = (const float*)d_in[1];
  const float* b_qkv = (const float*)d_in[2];
  const float* a_qkv = (const float*)d_in[3];
  const float* g_qkv = (const float*)d_in[4];
  const float* be_qkv = (const float*)d_in[5];
  const float* w_proj = (const float*)d_in[6];
  const float* b_proj = (const float*)d_in[7];
  const float* a_proj = (const float*)d_in[8];
  const float* g_proj = (const float*)d_in[9];
  const float* be_proj = (const float*)d_in[10];
  float* out = (float*)d_out;

  short* wqb = (short*)d_ws;                       // 512*256 bf16
  short* wpb = wqb + 512 * 256;                    // 256*256 bf16
  short* xbt = wpb + 256 * 256;                    // 32000*256 bf16
  float* hbuf = (float*)(xbt + (size_t)32000 * 256);  // 32*1000*512 fp32
  float* ctxf = hbuf + (size_t)32 * T_DIM * 512;      // 32000*256 fp32

  cvt_bf16<<<512, 256, 0, stream>>>(w_qkv, wqb, 512 * 256);
  cvt_bf16<<<256, 256, 0, stream>>>(w_proj, wpb, 256 * 256);
  xpose_x<<<dim3(4, 16, 32), 256, 0, stream>>>(x, xbt);
  qkv_mfma<<<1000, 256, 0, stream>>>(xbt, wqb, b_qkv, a_qkv, g_qkv, be_qkv,
                                     hbuf);
  attn_kernel<<<dim3(125, 32), 128, 0, stream>>>(hbuf, ctxf);
  proj_mfma<<<1024, 256, 0, stream>>>(ctxf, wpb, b_proj, a_proj, g_proj,
                                      be_proj, out);
}

// Round 4
// 201.201 us; speedup vs baseline: 4.1427x; 1.4175x over previous
//
#include <hip/hip_runtime.h>
#include <math.h>

#define T_DIM 1000

typedef __attribute__((ext_vector_type(8))) short short8;
typedef __attribute__((ext_vector_type(16))) float f32x16;

static __device__ __forceinline__ short bf16_rn(float f) {
  union { float f; unsigned u; } v;
  v.f = f;
  unsigned r = v.u + 0x7fffu + ((v.u >> 16) & 1u);
  return (short)(r >> 16);
}

__global__ __launch_bounds__(256) void cvt_bf16(const float* __restrict__ in,
                                                short* __restrict__ out,
                                                int n) {
  int i = blockIdx.x * 256 + threadIdx.x;
  if (i < n) out[i] = bf16_rn(in[i]);
}

// x[b][c][f][t] fp32 -> xbt[(b*T+t)*8+f][256] bf16
__global__ __launch_bounds__(256) void xpose_x(const float* __restrict__ x,
                                               short* __restrict__ xbt) {
  __shared__ float tile[64][65];
  int bf = blockIdx.z;  // b*8+f
  int b = bf >> 3, f = bf & 7;
  int c0 = blockIdx.x * 64, t0 = blockIdx.y * 64;
  int tid = threadIdx.x;
  int tc = tid & 63;
  int t = t0 + tc;
  if (t < T_DIM) {
    int sg = tid >> 6;  // 0..3
#pragma unroll
    for (int i = 0; i < 16; ++i) {
      int cr = i * 4 + sg;
      tile[cr][tc] = x[((size_t)(b * 256 + c0 + cr) * 8 + f) * T_DIM + t];
    }
  }
  __syncthreads();
  int tr = tid >> 2, cg = (tid & 3) * 16;
  int tt = t0 + tr;
  if (tt < T_DIM) {
    short tmp[16];
#pragma unroll
    for (int i = 0; i < 16; ++i) tmp[i] = bf16_rn(tile[cg + i][tr]);
    short* dst = xbt + ((size_t)((b * T_DIM + tt) * 8 + f)) * 256 + c0 + cg;
    *(short8*)dst = *(short8*)tmp;
    *(short8*)(dst + 8) = *(short8*)(tmp + 8);
  }
}

// ---------------- QKV: MFMA GEMM M=512 K=256 Ntile=64 + bias/PReLU/LN ------
// Writes bf16:  qk[bh][lo][t][f]  (lo<32: q chans 0-15, k chans 16-31)
//               vp[bh][t>>3][f*32+(lo-32)][t&7]  (lo>=32)
__global__ __launch_bounds__(256) void qkv_mfma(
    const short* __restrict__ xbt, const short* __restrict__ wb,
    const float* __restrict__ bias, const float* __restrict__ a_p,
    const float* __restrict__ gam, const float* __restrict__ bet,
    short* __restrict__ qkb, short* __restrict__ vpb) {
  __shared__ short Bs[64][264];
  __shared__ float lnS[4][2][32], lnQ[4][2][32];
  __shared__ float mu_s[2][32], ri_s[2][32];
  __shared__ float pb[512], pg[512], pe[512];
  int tid = threadIdx.x;
  int n0 = blockIdx.x * 64;
  int b = n0 / 8000;
  for (int i = tid; i < 512; i += 256) {
    pb[i] = bias[i];
    pg[i] = gam[i];
    pe[i] = bet[i];
  }
#pragma unroll
  for (int i = 0; i < 4; ++i) {
    int row = 16 * i + (tid >> 4);
    int off = (tid & 15) * 16;
    const short8* src = (const short8*)(xbt + (size_t)(n0 + row) * 256 + off);
    *(short8*)&Bs[row][off] = src[0];
    *(short8*)&Bs[row][off + 8] = src[1];
  }
  __syncthreads();
  int lane = tid & 63, wv = tid >> 6;
  int h = lane >> 5, l31 = lane & 31;
  int m0 = wv * 128;
  f32x16 acc[4][2];
#pragma unroll
  for (int mt = 0; mt < 4; ++mt)
#pragma unroll
    for (int nt = 0; nt < 2; ++nt)
#pragma unroll
      for (int r = 0; r < 16; ++r) acc[mt][nt][r] = 0.f;
  const short* wbase = wb + ((size_t)(m0 + l31)) * 256 + h * 8;
#pragma unroll
  for (int kk = 0; kk < 16; ++kk) {
    short8 bfr0 = *(const short8*)&Bs[l31][kk * 16 + h * 8];
    short8 bfr1 = *(const short8*)&Bs[32 + l31][kk * 16 + h * 8];
#pragma unroll
    for (int mt = 0; mt < 4; ++mt) {
      short8 af = *(const short8*)(wbase + (size_t)mt * 32 * 256 + kk * 16);
      acc[mt][0] =
          __builtin_amdgcn_mfma_f32_32x32x16_bf16(af, bfr0, acc[mt][0], 0, 0, 0);
      acc[mt][1] =
          __builtin_amdgcn_mfma_f32_32x32x16_bf16(af, bfr1, acc[mt][1], 0, 0, 0);
    }
  }
  float aslope = a_p[0];
  float sm[2] = {0.f, 0.f}, sq[2] = {0.f, 0.f};
#pragma unroll
  for (int mt = 0; mt < 4; ++mt) {
#pragma unroll
    for (int nt = 0; nt < 2; ++nt) {
#pragma unroll
      for (int r = 0; r < 16; ++r) {
        int row = (r & 3) + 8 * (r >> 2) + 4 * h;
        int o = m0 + mt * 32 + row;
        float v = acc[mt][nt][r] + pb[o];
        v = v >= 0.f ? v : aslope * v;
        acc[mt][nt][r] = v;
        sm[nt] += v;
        sq[nt] += v * v;
      }
    }
  }
#pragma unroll
  for (int nt = 0; nt < 2; ++nt) {
    sm[nt] += __shfl_xor(sm[nt], 32, 64);
    sq[nt] += __shfl_xor(sq[nt], 32, 64);
    if (h == 0) {
      lnS[wv][nt][l31] = sm[nt];
      lnQ[wv][nt][l31] = sq[nt];
    }
  }
  __syncthreads();
  if (tid < 64) {
    int nt = tid >> 5, c = tid & 31;
    float ss = lnS[0][nt][c] + lnS[1][nt][c] + lnS[2][nt][c] + lnS[3][nt][c];
    float qq = lnQ[0][nt][c] + lnQ[1][nt][c] + lnQ[2][nt][c] + lnQ[3][nt][c];
    float mu = ss * (1.f / 512.f);
    float var = qq * (1.f / 512.f) - mu * mu;
    mu_s[nt][c] = mu;
    ri_s[nt][c] = rsqrtf(var + 1e-5f);
  }
  __syncthreads();
#pragma unroll
  for (int nt = 0; nt < 2; ++nt) {
    float mu = mu_s[nt][l31], ri = ri_s[nt][l31];
    int n = n0 + nt * 32 + l31;
    int t = (n >> 3) - b * T_DIM;
    int f = n & 7;
#pragma unroll
    for (int mt = 0; mt < 4; ++mt) {
#pragma unroll
      for (int r = 0; r < 16; ++r) {
        int row = (r & 3) + 8 * (r >> 2) + 4 * h;
        int o = m0 + mt * 32 + row;
        float v = (acc[mt][nt][r] - mu) * ri * pg[o] + pe[o];
        short bv = bf16_rn(v);
        int head = o >> 6, lo = o & 63;
        int bh = b * 8 + head;
        if (lo < 32) {
          qkb[((size_t)(bh * 32 + lo) * 1024 + t) * 8 + f] = bv;
        } else {
          vpb[((size_t)(bh * 128 + (t >> 3)) * 256 + f * 32 + (lo - 32)) * 8 +
              (t & 7)] = bv;
        }
      }
    }
  }
}

// ---------------- attention: MFMA flash, 1 wave = 32 queries ---------------
// qk[bh][c][t][f]: c<16 = q chan-blk, c in [16,32) = k chan-blk.
// vp[bh][s>>3][f*32+vh][s&7].  Out: ctxb[(b*8+f)*T + t][h*32+vh] bf16.
__global__ __launch_bounds__(128) void attn_mfma(const short* __restrict__ qkb,
                                                 const short* __restrict__ vpb,
                                                 short* __restrict__ ctxb) {
  int bh = blockIdx.y;
  int wv = threadIdx.x >> 6;
  int qt0 = blockIdx.x * 64 + wv * 32;
  int lane = threadIdx.x & 63;
  int l31 = lane & 31, h = lane >> 5;
  int b = bh >> 3, hh = bh & 7;
  const short* qbase = qkb + (size_t)bh * 32 * 1024 * 8;
  // Q B-frags (reused across key tiles)
  short8 qf[8];
#pragma unroll
  for (int kk = 0; kk < 8; ++kk) {
    int qc = 2 * kk + h;
    qf[kk] = *(const short8*)(qbase + ((size_t)qc * 1024 + qt0 + l31) * 8);
  }
  int ks_lo = qt0 > 100 ? ((qt0 - 100) & ~31) : 0;
  int kt_n = (qt0 + 32 - ks_lo) >> 5;  // <= 5
  f32x16 S[5];
#pragma unroll
  for (int kt = 0; kt < 5; ++kt) {
#pragma unroll
    for (int r = 0; r < 16; ++r) S[kt][r] = 0.f;
    if (kt < kt_n) {
      int sb = ks_lo + kt * 32;
#pragma unroll
      for (int kk = 0; kk < 8; ++kk) {
        int kc = 16 + 2 * kk + h;
        short8 kf =
            *(const short8*)(qbase + ((size_t)kc * 1024 + sb + l31) * 8);
        S[kt] = __builtin_amdgcn_mfma_f32_32x32x16_bf16(kf, qf[kk], S[kt], 0, 0, 0);
      }
    }
  }
  // mask + scale + max
  int q_t = qt0 + l31;
  float m = -INFINITY;
#pragma unroll
  for (int kt = 0; kt < 5; ++kt) {
    if (kt < kt_n) {
      int sb = ks_lo + kt * 32;
#pragma unroll
      for (int r = 0; r < 16; ++r) {
        int s = sb + (r & 3) + 8 * (r >> 2) + 4 * h;
        float v = S[kt][r] * 0.08838834764831843f;
        bool ok = (s <= q_t) && (s + 100 >= q_t);
        v = ok ? v : -INFINITY;
        S[kt][r] = v;
        m = fmaxf(m, v);
      }
    }
  }
  m = fmaxf(m, __shfl_xor(m, 32, 64));
  float lsum = 0.f;
#pragma unroll
  for (int kt = 0; kt < 5; ++kt) {
    if (kt < kt_n) {
#pragma unroll
      for (int r = 0; r < 16; ++r) {
        float e = __expf(S[kt][r] - m);
        S[kt][r] = e;
        lsum += e;
      }
    }
  }
  lsum += __shfl_xor(lsum, 32, 64);
  float inv = 1.f / lsum;
  // P -> A-frags via shfl_xor(32): frag j / j+4 share reg r=(j&3)+4*(2ks+h)
  short8 pf[10];
#pragma unroll
  for (int kt = 0; kt < 5; ++kt) {
    if (kt < kt_n) {
#pragma unroll
      for (int ks2 = 0; ks2 < 2; ++ks2) {
        short8 fr;
#pragma unroll
        for (int jj = 0; jj < 4; ++jj) {
          int rA = 8 * ks2 + jj, rB = rA + 4;
          short a16 = bf16_rn(S[kt][rA] * inv);
          short b16 = bf16_rn(S[kt][rB] * inv);
          int pk = (int)(unsigned short)a16 | (((int)b16) << 16);
          int xp = __shfl_xor(pk, 32, 64);
          fr[jj] = h == 0 ? a16 : (short)(xp >> 16);
          fr[4 + jj] = h == 0 ? (short)(xp & 0xffff) : b16;
        }
        pf[kt * 2 + ks2] = fr;
      }
    }
  }
  // PV: O = P * V, one N-tile (=freq f) at a time; store direct (coalesced)
  const short* vbase = vpb + (size_t)bh * 128 * 256 * 8;
#pragma unroll
  for (int nt = 0; nt < 8; ++nt) {
    f32x16 acc;
#pragma unroll
    for (int r = 0; r < 16; ++r) acc[r] = 0.f;
#pragma unroll
    for (int kt = 0; kt < 5; ++kt) {
      if (kt < kt_n) {
#pragma unroll
        for (int ks2 = 0; ks2 < 2; ++ks2) {
          int sb = ks_lo + kt * 32 + ks2 * 16 + h * 8;
          short8 vf = *(const short8*)(vbase +
                                       ((size_t)(sb >> 3) * 256 + nt * 32 + l31) * 8);
          acc = __builtin_amdgcn_mfma_f32_32x32x16_bf16(pf[kt * 2 + ks2], vf,
                                                        acc, 0, 0, 0);
        }
      }
    }
    short* crow = ctxb + ((size_t)(b * 8 + nt) * T_DIM) * 256 + hh * 32 + l31;
#pragma unroll
    for (int r = 0; r < 16; ++r) {
      int t = qt0 + (r & 3) + 8 * (r >> 2) + 4 * h;
      if (t < T_DIM) crow[(size_t)t * 256] = bf16_rn(acc[r]);
    }
  }
}

// ---------------- proj: MFMA GEMM M=256 K=256 Ntile=32 + bias/PReLU/LN -----
__global__ __launch_bounds__(256) void proj_mfma(
    const short* __restrict__ ctxb, const short* __restrict__ wb,
    const float* __restrict__ bias, const float* __restrict__ a_p,
    const float* __restrict__ gam, const float* __restrict__ bet,
    float* __restrict__ out) {
  __shared__ short Bs[32][264];
  __shared__ float lnS[4][32], lnQ[4][32];
  __shared__ float mu_s[32], ri_s[32];
  __shared__ float pb[256], pg[256], pe[256];
  int tid = threadIdx.x;
  int blk = blockIdx.x;
  int bf = blk >> 5, tb = blk & 31;
  int b = bf >> 3, f = bf & 7;
  int t0 = tb * 32;
  pb[tid] = bias[tid];
  pg[tid] = gam[tid];
  pe[tid] = bet[tid];
  {
    int n = tid >> 3, ch = tid & 7;
    int t = t0 + n;
    if (t < T_DIM) {
      const short8* src =
          (const short8*)(ctxb + ((size_t)bf * T_DIM + t) * 256 + ch * 32);
#pragma unroll
      for (int j = 0; j < 4; ++j) *(short8*)&Bs[n][ch * 32 + 8 * j] = src[j];
    } else {
      short8 z = {0, 0, 0, 0, 0, 0, 0, 0};
#pragma unroll
      for (int j = 0; j < 4; ++j) *(short8*)&Bs[n][ch * 32 + 8 * j] = z;
    }
  }
  __syncthreads();
  int lane = tid & 63, wv = tid >> 6;
  int half = lane >> 5, ln32 = lane & 31;
  int m0 = wv * 64;
  f32x16 acc[2];
#pragma unroll
  for (int mt = 0; mt < 2; ++mt)
#pragma unroll
    for (int r = 0; r < 16; ++r) acc[mt][r] = 0.f;
  const short* wbase = wb + ((size_t)(m0 + ln32)) * 256 + half * 8;
#pragma unroll
  for (int kk = 0; kk < 16; ++kk) {
    int k0 = kk * 16;
    short8 bfrag = *(const short8*)&Bs[ln32][k0 + half * 8];
#pragma unroll
    for (int mt = 0; mt < 2; ++mt) {
      short8 afrag = *(const short8*)(wbase + (size_t)mt * 32 * 256 + k0);
      acc[mt] =
          __builtin_amdgcn_mfma_f32_32x32x16_bf16(afrag, bfrag, acc[mt], 0, 0, 0);
    }
  }
  float aslope = a_p[0];
  float s = 0.f, q = 0.f;
#pragma unroll
  for (int mt = 0; mt < 2; ++mt) {
#pragma unroll
    for (int r = 0; r < 16; ++r) {
      int row = (r & 3) + 8 * (r >> 2) + 4 * half;
      int o = m0 + mt * 32 + row;
      float v = acc[mt][r] + pb[o];
      v = v >= 0.f ? v : aslope * v;
      acc[mt][r] = v;
      s += v;
      q += v * v;
    }
  }
  s += __shfl_xor(s, 32, 64);
  q += __shfl_xor(q, 32, 64);
  if (half == 0) {
    lnS[wv][ln32] = s;
    lnQ[wv][ln32] = q;
  }
  __syncthreads();
  if (tid < 32) {
    float ss = lnS[0][tid] + lnS[1][tid] + lnS[2][tid] + lnS[3][tid];
    float qq = lnQ[0][tid] + lnQ[1][tid] + lnQ[2][tid] + lnQ[3][tid];
    float mu = ss * (1.f / 256.f);
    float var = qq * (1.f / 256.f) - mu * mu;
    mu_s[tid] = mu;
    ri_s[tid] = rsqrtf(var + 1e-5f);
  }
  __syncthreads();
  float mu = mu_s[ln32], ri = ri_s[ln32];
  int t = t0 + ln32;
  if (t < T_DIM) {
#pragma unroll
    for (int mt = 0; mt < 2; ++mt) {
#pragma unroll
      for (int r = 0; r < 16; ++r) {
        int row = (r & 3) + 8 * (r >> 2) + 4 * half;
        int o = m0 + mt * 32 + row;
        float v = (acc[mt][r] - mu) * ri * pg[o] + pe[o];
        out[((size_t)(b * 2048 + o * 8 + f)) * T_DIM + t] = v;
      }
    }
  }
}

extern "C" void kernel_launch(void* const* d_in, const int* in_sizes, int n_in,
                              void* d_out, int out_size, void* d_ws,
                              size_t ws_size, hipStream_t stream) {
  const float* x = (const float*)d_in[0];
  const float* w_qkv = (const float*)d_in[1];
  const float* b_qkv = (const float*)d_in[2];
  const float* a_qkv = (const float*)d_in[3];
  const float* g_qkv = (const float*)d_in[4];
  const float* be_qkv = (const float*)d_in[5];
  const float* w_proj = (const float*)d_in[6];
  const float* b_proj = (const float*)d_in[7];
  const float* a_proj = (const float*)d_in[8];
  const float* g_proj = (const float*)d_in[9];
  const float* be_proj = (const float*)d_in[10];
  float* out = (float*)d_out;

  short* wqb = (short*)d_ws;                      // 512*256
  short* wpb = wqb + 131072;                      // 256*256
  short* xbt = wpb + 65536;                       // 32000*256
  short* qkb = xbt + (size_t)8192000;             // 32*32*1024*8
  short* vpb = qkb + (size_t)8388608;             // 32*128*256*8
  short* ctxb = vpb + (size_t)8388608;            // 32000*256

  cvt_bf16<<<512, 256, 0, stream>>>(w_qkv, wqb, 512 * 256);
  cvt_bf16<<<256, 256, 0, stream>>>(w_proj, wpb, 256 * 256);
  xpose_x<<<dim3(4, 16, 32), 256, 0, stream>>>(x, xbt);
  qkv_mfma<<<500, 256, 0, stream>>>(xbt, wqb, b_qkv, a_qkv, g_qkv, be_qkv,
                                    qkb, vpb);
  attn_mfma<<<dim3(16, 32), 128, 0, stream>>>(qkb, vpb, ctxb);
  proj_mfma<<<1024, 256, 0, stream>>>(ctxb, wpb, b_proj, a_proj, g_proj,
                                      be_proj, out);
}

// Round 5
// 184.252 us; speedup vs baseline: 4.5238x; 1.0920x over previous
//
#include <hip/hip_runtime.h>
#include <math.h>

#define T_DIM 1000

typedef __attribute__((ext_vector_type(8))) short short8;
typedef __attribute__((ext_vector_type(16))) float f32x16;

static __device__ __forceinline__ short bf16_rn(float f) {
  union { float f; unsigned u; } v;
  v.f = f;
  unsigned r = v.u + 0x7fffu + ((v.u >> 16) & 1u);
  return (short)(r >> 16);
}

__global__ __launch_bounds__(256) void cvt_bf16(const float* __restrict__ in,
                                                short* __restrict__ out,
                                                int n) {
  int i = blockIdx.x * 256 + threadIdx.x;
  if (i < n) out[i] = bf16_rn(in[i]);
}

// x[b][c][f][t] fp32 -> xbt[(b*T+t)*8+f][256] bf16
__global__ __launch_bounds__(256) void xpose_x(const float* __restrict__ x,
                                               short* __restrict__ xbt) {
  __shared__ float tile[64][65];
  int bf = blockIdx.z;  // b*8+f
  int b = bf >> 3, f = bf & 7;
  int c0 = blockIdx.x * 64, t0 = blockIdx.y * 64;
  int tid = threadIdx.x;
  int tc = tid & 63;
  int t = t0 + tc;
  if (t < T_DIM) {
    int sg = tid >> 6;  // 0..3
#pragma unroll
    for (int i = 0; i < 16; ++i) {
      int cr = i * 4 + sg;
      tile[cr][tc] = x[((size_t)(b * 256 + c0 + cr) * 8 + f) * T_DIM + t];
    }
  }
  __syncthreads();
  int tr = tid >> 2, cg = (tid & 3) * 16;
  int tt = t0 + tr;
  if (tt < T_DIM) {
    short tmp[16];
#pragma unroll
    for (int i = 0; i < 16; ++i) tmp[i] = bf16_rn(tile[cg + i][tr]);
    short* dst = xbt + ((size_t)((b * T_DIM + tt) * 8 + f)) * 256 + c0 + cg;
    *(short8*)dst = *(short8*)tmp;
    *(short8*)(dst + 8) = *(short8*)(tmp + 8);
  }
}

// ---------------- QKV: MFMA GEMM M=512 K=256 Ntile=64, 8 waves -------------
// wave wv: M rows [wv*64, wv*64+64), all 64 cols. acc = 4 f32x16 (~110 VGPR).
__global__ __launch_bounds__(512) void qkv_mfma(
    const short* __restrict__ xbt, const short* __restrict__ wb,
    const float* __restrict__ bias, const float* __restrict__ a_p,
    const float* __restrict__ gam, const float* __restrict__ bet,
    short* __restrict__ qkb, short* __restrict__ vpb) {
  __shared__ short Bs[64][264];
  __shared__ float lnS[8][2][32], lnQ[8][2][32];
  __shared__ float mu_s[2][32], ri_s[2][32];
  __shared__ float pb[512], pg[512], pe[512];
  int tid = threadIdx.x;
  int n0 = blockIdx.x * 64;
  int b = n0 / 8000;
  pb[tid] = bias[tid];
  pg[tid] = gam[tid];
  pe[tid] = bet[tid];
  {
    int row = tid >> 3, ch = tid & 7;
    const short8* src =
        (const short8*)(xbt + (size_t)(n0 + row) * 256 + ch * 32);
    *(short8*)&Bs[row][ch * 32] = src[0];
    *(short8*)&Bs[row][ch * 32 + 8] = src[1];
    *(short8*)&Bs[row][ch * 32 + 16] = src[2];
    *(short8*)&Bs[row][ch * 32 + 24] = src[3];
  }
  __syncthreads();
  int lane = tid & 63, wv = tid >> 6;  // wv 0..7
  int h = lane >> 5, l31 = lane & 31;
  int m0 = wv * 64;
  f32x16 acc[2][2];
#pragma unroll
  for (int mt = 0; mt < 2; ++mt)
#pragma unroll
    for (int nt = 0; nt < 2; ++nt)
#pragma unroll
      for (int r = 0; r < 16; ++r) acc[mt][nt][r] = 0.f;
  const short* wbase = wb + ((size_t)(m0 + l31)) * 256 + h * 8;
#pragma unroll
  for (int kk = 0; kk < 16; ++kk) {
    short8 bfr0 = *(const short8*)&Bs[l31][kk * 16 + h * 8];
    short8 bfr1 = *(const short8*)&Bs[32 + l31][kk * 16 + h * 8];
#pragma unroll
    for (int mt = 0; mt < 2; ++mt) {
      short8 af = *(const short8*)(wbase + (size_t)mt * 32 * 256 + kk * 16);
      acc[mt][0] =
          __builtin_amdgcn_mfma_f32_32x32x16_bf16(af, bfr0, acc[mt][0], 0, 0, 0);
      acc[mt][1] =
          __builtin_amdgcn_mfma_f32_32x32x16_bf16(af, bfr1, acc[mt][1], 0, 0, 0);
    }
  }
  float aslope = a_p[0];
  float sm[2] = {0.f, 0.f}, sq[2] = {0.f, 0.f};
#pragma unroll
  for (int mt = 0; mt < 2; ++mt) {
#pragma unroll
    for (int nt = 0; nt < 2; ++nt) {
#pragma unroll
      for (int r = 0; r < 16; ++r) {
        int row = (r & 3) + 8 * (r >> 2) + 4 * h;
        int o = m0 + mt * 32 + row;
        float v = acc[mt][nt][r] + pb[o];
        v = v >= 0.f ? v : aslope * v;
        acc[mt][nt][r] = v;
        sm[nt] += v;
        sq[nt] += v * v;
      }
    }
  }
#pragma unroll
  for (int nt = 0; nt < 2; ++nt) {
    sm[nt] += __shfl_xor(sm[nt], 32, 64);
    sq[nt] += __shfl_xor(sq[nt], 32, 64);
    if (h == 0) {
      lnS[wv][nt][l31] = sm[nt];
      lnQ[wv][nt][l31] = sq[nt];
    }
  }
  __syncthreads();
  if (tid < 64) {
    int nt = tid >> 5, c = tid & 31;
    float ss = 0.f, qq = 0.f;
#pragma unroll
    for (int w = 0; w < 8; ++w) {
      ss += lnS[w][nt][c];
      qq += lnQ[w][nt][c];
    }
    float mu = ss * (1.f / 512.f);
    float var = qq * (1.f / 512.f) - mu * mu;
    mu_s[nt][c] = mu;
    ri_s[nt][c] = rsqrtf(var + 1e-5f);
  }
  __syncthreads();
#pragma unroll
  for (int nt = 0; nt < 2; ++nt) {
    float mu = mu_s[nt][l31], ri = ri_s[nt][l31];
    int n = n0 + nt * 32 + l31;
    int t = (n >> 3) - b * T_DIM;
    int f = n & 7;
#pragma unroll
    for (int mt = 0; mt < 2; ++mt) {
#pragma unroll
      for (int r = 0; r < 16; ++r) {
        int row = (r & 3) + 8 * (r >> 2) + 4 * h;
        int o = m0 + mt * 32 + row;
        float v = (acc[mt][nt][r] - mu) * ri * pg[o] + pe[o];
        short bv = bf16_rn(v);
        int head = o >> 6, lo = o & 63;
        int bh = b * 8 + head;
        if (lo < 32) {
          qkb[((size_t)(bh * 32 + lo) * 1024 + t) * 8 + f] = bv;
        } else {
          vpb[((size_t)(bh * 128 + (t >> 3)) * 256 + f * 32 + (lo - 32)) * 8 +
              (t & 7)] = bv;
        }
      }
    }
  }
}

// ---------------- attention: MFMA flash, 4 waves cooperate on 32 queries ---
// qk[bh][c][t][f]: c<16 = q chan-blk, c in [16,32) = k chan-blk.
// vp[bh][s>>3][f*32+vh][s&7].  Out: ctxb[(b*8+f)*T + t][h*32+vh] bf16.
__global__ __launch_bounds__(256) void attn_mfma(const short* __restrict__ qkb,
                                                 const short* __restrict__ vpb,
                                                 short* __restrict__ ctxb) {
  __shared__ short pbuf[10][64 * 8];  // P A-frags, [frag][lane*8]
  __shared__ float wmax[4][32], wsum[4][32];
  int bh = blockIdx.y;
  int qt0 = blockIdx.x * 32;
  int tid = threadIdx.x;
  int wv = tid >> 6, lane = tid & 63;
  int l31 = lane & 31, h = lane >> 5;
  int b = bh >> 3, hh = bh & 7;
  const short* qbase = qkb + (size_t)bh * 32 * 1024 * 8;
  short8 qf[8];
#pragma unroll
  for (int kk = 0; kk < 8; ++kk) {
    int qc = 2 * kk + h;
    qf[kk] = *(const short8*)(qbase + ((size_t)qc * 1024 + qt0 + l31) * 8);
  }
  int ks_lo = qt0 > 100 ? ((qt0 - 100) & ~31) : 0;
  int kt_n = (qt0 + 32 - ks_lo) >> 5;  // 1..5 (block-uniform)
  int kt0 = wv, kt1 = wv + 4;
  bool has0 = kt0 < kt_n, has1 = kt1 < kt_n;
  int q_t = qt0 + l31;
  f32x16 S0, S1;
  float pm = -INFINITY;
  if (has0) {
#pragma unroll
    for (int r = 0; r < 16; ++r) S0[r] = 0.f;
    int sb = ks_lo + kt0 * 32;
#pragma unroll
    for (int kk = 0; kk < 8; ++kk) {
      int kc = 16 + 2 * kk + h;
      short8 kf = *(const short8*)(qbase + ((size_t)kc * 1024 + sb + l31) * 8);
      S0 = __builtin_amdgcn_mfma_f32_32x32x16_bf16(kf, qf[kk], S0, 0, 0, 0);
    }
#pragma unroll
    for (int r = 0; r < 16; ++r) {
      int s = sb + (r & 3) + 8 * (r >> 2) + 4 * h;
      float v = S0[r] * 0.08838834764831843f;
      bool ok = (s <= q_t) && (s + 100 >= q_t);
      v = ok ? v : -INFINITY;
      S0[r] = v;
      pm = fmaxf(pm, v);
    }
  }
  if (has1) {
#pragma unroll
    for (int r = 0; r < 16; ++r) S1[r] = 0.f;
    int sb = ks_lo + kt1 * 32;
#pragma unroll
    for (int kk = 0; kk < 8; ++kk) {
      int kc = 16 + 2 * kk + h;
      short8 kf = *(const short8*)(qbase + ((size_t)kc * 1024 + sb + l31) * 8);
      S1 = __builtin_amdgcn_mfma_f32_32x32x16_bf16(kf, qf[kk], S1, 0, 0, 0);
    }
#pragma unroll
    for (int r = 0; r < 16; ++r) {
      int s = sb + (r & 3) + 8 * (r >> 2) + 4 * h;
      float v = S1[r] * 0.08838834764831843f;
      bool ok = (s <= q_t) && (s + 100 >= q_t);
      v = ok ? v : -INFINITY;
      S1[r] = v;
      pm = fmaxf(pm, v);
    }
  }
  pm = fmaxf(pm, __shfl_xor(pm, 32, 64));
  if (h == 0) wmax[wv][l31] = pm;
  __syncthreads();
  float gm = fmaxf(fmaxf(wmax[0][l31], wmax[1][l31]),
                   fmaxf(wmax[2][l31], wmax[3][l31]));
  float ws = 0.f;
  if (has0) {
#pragma unroll
    for (int r = 0; r < 16; ++r) {
      float e = __expf(S0[r] - gm);
      S0[r] = e;
      ws += e;
    }
  }
  if (has1) {
#pragma unroll
    for (int r = 0; r < 16; ++r) {
      float e = __expf(S1[r] - gm);
      S1[r] = e;
      ws += e;
    }
  }
  ws += __shfl_xor(ws, 32, 64);
  if (h == 0) wsum[wv][l31] = ws;
  __syncthreads();
  float inv =
      1.f / (wsum[0][l31] + wsum[1][l31] + wsum[2][l31] + wsum[3][l31]);
  // pack P -> A-frags (shfl_xor 32 pairing) and stash in LDS
  if (has0) {
#pragma unroll
    for (int ks2 = 0; ks2 < 2; ++ks2) {
      short tmp8[8];
#pragma unroll
      for (int jj = 0; jj < 4; ++jj) {
        int rA = 8 * ks2 + jj, rB = rA + 4;
        short a16 = bf16_rn(S0[rA] * inv);
        short b16 = bf16_rn(S0[rB] * inv);
        int pk = (int)(unsigned short)a16 | (((int)b16) << 16);
        int xp = __shfl_xor(pk, 32, 64);
        tmp8[jj] = h == 0 ? a16 : (short)(xp >> 16);
        tmp8[4 + jj] = h == 0 ? (short)(xp & 0xffff) : b16;
      }
      *(short8*)&pbuf[kt0 * 2 + ks2][lane * 8] = *(short8*)tmp8;
    }
  }
  if (has1) {
#pragma unroll
    for (int ks2 = 0; ks2 < 2; ++ks2) {
      short tmp8[8];
#pragma unroll
      for (int jj = 0; jj < 4; ++jj) {
        int rA = 8 * ks2 + jj, rB = rA + 4;
        short a16 = bf16_rn(S1[rA] * inv);
        short b16 = bf16_rn(S1[rB] * inv);
        int pk = (int)(unsigned short)a16 | (((int)b16) << 16);
        int xp = __shfl_xor(pk, 32, 64);
        tmp8[jj] = h == 0 ? a16 : (short)(xp >> 16);
        tmp8[4 + jj] = h == 0 ? (short)(xp & 0xffff) : b16;
      }
      *(short8*)&pbuf[kt1 * 2 + ks2][lane * 8] = *(short8*)tmp8;
    }
  }
  __syncthreads();
  // PV: each wave covers nt = 2*wv, 2*wv+1 (freqs)
  const short* vbase = vpb + (size_t)bh * 128 * 256 * 8;
#pragma unroll
  for (int j = 0; j < 2; ++j) {
    int nt = wv * 2 + j;
    f32x16 acc;
#pragma unroll
    for (int r = 0; r < 16; ++r) acc[r] = 0.f;
    for (int kt = 0; kt < kt_n; ++kt) {
#pragma unroll
      for (int ks2 = 0; ks2 < 2; ++ks2) {
        short8 pfr = *(const short8*)&pbuf[kt * 2 + ks2][lane * 8];
        int sb = ks_lo + kt * 32 + ks2 * 16 + h * 8;
        short8 vf = *(const short8*)(vbase +
                                     ((size_t)(sb >> 3) * 256 + nt * 32 + l31) * 8);
        acc = __builtin_amdgcn_mfma_f32_32x32x16_bf16(pfr, vf, acc, 0, 0, 0);
      }
    }
    short* crow = ctxb + ((size_t)(b * 8 + nt) * T_DIM) * 256 + hh * 32 + l31;
#pragma unroll
    for (int r = 0; r < 16; ++r) {
      int t = qt0 + (r & 3) + 8 * (r >> 2) + 4 * h;
      if (t < T_DIM) crow[(size_t)t * 256] = bf16_rn(acc[r]);
    }
  }
}

// ---------------- proj: MFMA GEMM M=256 K=256 Ntile=64, 4 waves ------------
// grid = bf(32) x tb(16); wave wv: M rows [wv*64, wv*64+64).
__global__ __launch_bounds__(256) void proj_mfma(
    const short* __restrict__ ctxb, const short* __restrict__ wb,
    const float* __restrict__ bias, const float* __restrict__ a_p,
    const float* __restrict__ gam, const float* __restrict__ bet,
    float* __restrict__ out) {
  __shared__ short Bs[64][264];
  __shared__ float lnS[4][2][32], lnQ[4][2][32];
  __shared__ float mu_s[2][32], ri_s[2][32];
  __shared__ float pb[256], pg[256], pe[256];
  int tid = threadIdx.x;
  int blk = blockIdx.x;
  int bf = blk >> 4, tb = blk & 15;
  int b = bf >> 3, f = bf & 7;
  int t0 = tb * 64;
  pb[tid] = bias[tid];
  pg[tid] = gam[tid];
  pe[tid] = bet[tid];
  {
    int row = tid >> 2, seg = (tid & 3) * 64;
    int t = t0 + row;
    if (t < T_DIM) {
      const short8* src =
          (const short8*)(ctxb + ((size_t)bf * T_DIM + t) * 256 + seg);
#pragma unroll
      for (int j = 0; j < 8; ++j) *(short8*)&Bs[row][seg + 8 * j] = src[j];
    } else {
      short8 z = {0, 0, 0, 0, 0, 0, 0, 0};
#pragma unroll
      for (int j = 0; j < 8; ++j) *(short8*)&Bs[row][seg + 8 * j] = z;
    }
  }
  __syncthreads();
  int lane = tid & 63, wv = tid >> 6;
  int h = lane >> 5, l31 = lane & 31;
  int m0 = wv * 64;
  f32x16 acc[2][2];
#pragma unroll
  for (int mt = 0; mt < 2; ++mt)
#pragma unroll
    for (int nt = 0; nt < 2; ++nt)
#pragma unroll
      for (int r = 0; r < 16; ++r) acc[mt][nt][r] = 0.f;
  const short* wbase = wb + ((size_t)(m0 + l31)) * 256 + h * 8;
#pragma unroll
  for (int kk = 0; kk < 16; ++kk) {
    short8 bfr0 = *(const short8*)&Bs[l31][kk * 16 + h * 8];
    short8 bfr1 = *(const short8*)&Bs[32 + l31][kk * 16 + h * 8];
#pragma unroll
    for (int mt = 0; mt < 2; ++mt) {
      short8 af = *(const short8*)(wbase + (size_t)mt * 32 * 256 + kk * 16);
      acc[mt][0] =
          __builtin_amdgcn_mfma_f32_32x32x16_bf16(af, bfr0, acc[mt][0], 0, 0, 0);
      acc[mt][1] =
          __builtin_amdgcn_mfma_f32_32x32x16_bf16(af, bfr1, acc[mt][1], 0, 0, 0);
    }
  }
  float aslope = a_p[0];
  float sm[2] = {0.f, 0.f}, sq[2] = {0.f, 0.f};
#pragma unroll
  for (int mt = 0; mt < 2; ++mt) {
#pragma unroll
    for (int nt = 0; nt < 2; ++nt) {
#pragma unroll
      for (int r = 0; r < 16; ++r) {
        int row = (r & 3) + 8 * (r >> 2) + 4 * h;
        int o = m0 + mt * 32 + row;
        float v = acc[mt][nt][r] + pb[o];
        v = v >= 0.f ? v : aslope * v;
        acc[mt][nt][r] = v;
        sm[nt] += v;
        sq[nt] += v * v;
      }
    }
  }
#pragma unroll
  for (int nt = 0; nt < 2; ++nt) {
    sm[nt] += __shfl_xor(sm[nt], 32, 64);
    sq[nt] += __shfl_xor(sq[nt], 32, 64);
    if (h == 0) {
      lnS[wv][nt][l31] = sm[nt];
      lnQ[wv][nt][l31] = sq[nt];
    }
  }
  __syncthreads();
  if (tid < 64) {
    int nt = tid >> 5, c = tid & 31;
    float ss = lnS[0][nt][c] + lnS[1][nt][c] + lnS[2][nt][c] + lnS[3][nt][c];
    float qq = lnQ[0][nt][c] + lnQ[1][nt][c] + lnQ[2][nt][c] + lnQ[3][nt][c];
    float mu = ss * (1.f / 256.f);
    float var = qq * (1.f / 256.f) - mu * mu;
    mu_s[nt][c] = mu;
    ri_s[nt][c] = rsqrtf(var + 1e-5f);
  }
  __syncthreads();
#pragma unroll
  for (int nt = 0; nt < 2; ++nt) {
    float mu = mu_s[nt][l31], ri = ri_s[nt][l31];
    int t = t0 + nt * 32 + l31;
    if (t < T_DIM) {
#pragma unroll
      for (int mt = 0; mt < 2; ++mt) {
#pragma unroll
        for (int r = 0; r < 16; ++r) {
          int row = (r & 3) + 8 * (r >> 2) + 4 * h;
          int o = m0 + mt * 32 + row;
          float v = (acc[mt][nt][r] - mu) * ri * pg[o] + pe[o];
          out[((size_t)(b * 2048 + o * 8 + f)) * T_DIM + t] = v;
        }
      }
    }
  }
}

extern "C" void kernel_launch(void* const* d_in, const int* in_sizes, int n_in,
                              void* d_out, int out_size, void* d_ws,
                              size_t ws_size, hipStream_t stream) {
  const float* x = (const float*)d_in[0];
  const float* w_qkv = (const float*)d_in[1];
  const float* b_qkv = (const float*)d_in[2];
  const float* a_qkv = (const float*)d_in[3];
  const float* g_qkv = (const float*)d_in[4];
  const float* be_qkv = (const float*)d_in[5];
  const float* w_proj = (const float*)d_in[6];
  const float* b_proj = (const float*)d_in[7];
  const float* a_proj = (const float*)d_in[8];
  const float* g_proj = (const float*)d_in[9];
  const float* be_proj = (const float*)d_in[10];
  float* out = (float*)d_out;

  short* wqb = (short*)d_ws;            // 512*256
  short* wpb = wqb + 131072;            // 256*256
  short* xbt = wpb + 65536;             // 32000*256
  short* qkb = xbt + (size_t)8192000;   // 32*32*1024*8
  short* vpb = qkb + (size_t)8388608;   // 32*128*256*8
  short* ctxb = vpb + (size_t)8388608;  // 32000*256

  cvt_bf16<<<512, 256, 0, stream>>>(w_qkv, wqb, 512 * 256);
  cvt_bf16<<<256, 256, 0, stream>>>(w_proj, wpb, 256 * 256);
  xpose_x<<<dim3(4, 16, 32), 256, 0, stream>>>(x, xbt);
  qkv_mfma<<<500, 512, 0, stream>>>(xbt, wqb, b_qkv, a_qkv, g_qkv, be_qkv,
                                    qkb, vpb);
  attn_mfma<<<dim3(32, 32), 256, 0, stream>>>(qkb, vpb, ctxb);
  proj_mfma<<<512, 256, 0, stream>>>(ctxb, wpb, b_proj, a_proj, g_proj,
                                     be_proj, out);
}

// Round 6
// 175.562 us; speedup vs baseline: 4.7477x; 1.0495x over previous
//
#include <hip/hip_runtime.h>
#include <math.h>

#define T_DIM 1000

typedef __attribute__((ext_vector_type(8))) short short8;
typedef __attribute__((ext_vector_type(16))) float f32x16;

static __device__ __forceinline__ short bf16_rn(float f) {
  union { float f; unsigned u; } v;
  v.f = f;
  unsigned r = v.u + 0x7fffu + ((v.u >> 16) & 1u);
  return (short)(r >> 16);
}

// weight conversion, both matrices in one launch (grid 768)
__global__ __launch_bounds__(256) void prep_w(const float* __restrict__ wq,
                                              const float* __restrict__ wp,
                                              short* __restrict__ wqb,
                                              short* __restrict__ wpb) {
  int i = blockIdx.x * 256 + threadIdx.x;
  if (i < 131072) wqb[i] = bf16_rn(wq[i]);
  int j = i - 131072;
  if (j >= 0 && j < 65536) wpb[j] = bf16_rn(wp[j]);
}

// ---------------- QKV: fused x-stage + MFMA GEMM M=512 K=256 Ntile=64 ------
// 8 waves; wave wv does M rows [wv*64, wv*64+64), all 64 cols.
// Stages x[b][c][f][t0..t0+7] directly into LDS B-tile (transpose + bf16).
__global__ __launch_bounds__(512) void qkv_mfma(
    const float* __restrict__ x, const short* __restrict__ wb,
    const float* __restrict__ bias, const float* __restrict__ a_p,
    const float* __restrict__ gam, const float* __restrict__ bet,
    short* __restrict__ qkb, short* __restrict__ vpb) {
  __shared__ short Bs[64][264];
  __shared__ float lnS[8][2][32], lnQ[8][2][32];
  __shared__ float mu_s[2][32], ri_s[2][32];
  __shared__ float pb[512], pg[512], pe[512];
  int tid = threadIdx.x;
  int blk = blockIdx.x;
  int b = blk / 125;
  int t0 = (blk * 8) % 1000;
  pb[tid] = bias[tid];
  pg[tid] = gam[tid];
  pe[tid] = bet[tid];
  {
    const float* xb = x + (size_t)b * 256 * 8000 + t0;
#pragma unroll
    for (int i = 0; i < 2; ++i) {
      int u = tid + i * 512;       // 0..1023
      int f = u & 7, cp = u >> 3;  // cp 0..127
      int c0 = cp * 2;
      const float* pa = xb + ((size_t)c0 * 8 + f) * 1000;
      const float* pbx = xb + ((size_t)(c0 + 1) * 8 + f) * 1000;
      float4 va0 = *(const float4*)pa;
      float4 va1 = *(const float4*)(pa + 4);
      float4 vb0 = *(const float4*)pbx;
      float4 vb1 = *(const float4*)(pbx + 4);
      float fa[8] = {va0.x, va0.y, va0.z, va0.w, va1.x, va1.y, va1.z, va1.w};
      float fb[8] = {vb0.x, vb0.y, vb0.z, vb0.w, vb1.x, vb1.y, vb1.z, vb1.w};
#pragma unroll
      for (int tt = 0; tt < 8; ++tt) {
        unsigned lo = (unsigned short)bf16_rn(fa[tt]);
        unsigned hi = (unsigned short)bf16_rn(fb[tt]);
        *(unsigned*)&Bs[tt * 8 + f][c0] = lo | (hi << 16);
      }
    }
  }
  __syncthreads();
  int lane = tid & 63, wv = tid >> 6;  // wv 0..7
  int h = lane >> 5, l31 = lane & 31;
  int m0 = wv * 64;
  f32x16 acc[2][2];
#pragma unroll
  for (int mt = 0; mt < 2; ++mt)
#pragma unroll
    for (int nt = 0; nt < 2; ++nt)
#pragma unroll
      for (int r = 0; r < 16; ++r) acc[mt][nt][r] = 0.f;
  const short* wbase = wb + ((size_t)(m0 + l31)) * 256 + h * 8;
#pragma unroll
  for (int kk = 0; kk < 16; ++kk) {
    short8 bfr0 = *(const short8*)&Bs[l31][kk * 16 + h * 8];
    short8 bfr1 = *(const short8*)&Bs[32 + l31][kk * 16 + h * 8];
#pragma unroll
    for (int mt = 0; mt < 2; ++mt) {
      short8 af = *(const short8*)(wbase + (size_t)mt * 32 * 256 + kk * 16);
      acc[mt][0] =
          __builtin_amdgcn_mfma_f32_32x32x16_bf16(af, bfr0, acc[mt][0], 0, 0, 0);
      acc[mt][1] =
          __builtin_amdgcn_mfma_f32_32x32x16_bf16(af, bfr1, acc[mt][1], 0, 0, 0);
    }
  }
  float aslope = a_p[0];
  float sm[2] = {0.f, 0.f}, sq[2] = {0.f, 0.f};
#pragma unroll
  for (int mt = 0; mt < 2; ++mt) {
#pragma unroll
    for (int nt = 0; nt < 2; ++nt) {
#pragma unroll
      for (int r = 0; r < 16; ++r) {
        int row = (r & 3) + 8 * (r >> 2) + 4 * h;
        int o = m0 + mt * 32 + row;
        float v = acc[mt][nt][r] + pb[o];
        v = v >= 0.f ? v : aslope * v;
        acc[mt][nt][r] = v;
        sm[nt] += v;
        sq[nt] += v * v;
      }
    }
  }
#pragma unroll
  for (int nt = 0; nt < 2; ++nt) {
    sm[nt] += __shfl_xor(sm[nt], 32, 64);
    sq[nt] += __shfl_xor(sq[nt], 32, 64);
    if (h == 0) {
      lnS[wv][nt][l31] = sm[nt];
      lnQ[wv][nt][l31] = sq[nt];
    }
  }
  __syncthreads();
  if (tid < 64) {
    int nt = tid >> 5, c = tid & 31;
    float ss = 0.f, qq = 0.f;
#pragma unroll
    for (int w = 0; w < 8; ++w) {
      ss += lnS[w][nt][c];
      qq += lnQ[w][nt][c];
    }
    float mu = ss * (1.f / 512.f);
    float var = qq * (1.f / 512.f) - mu * mu;
    mu_s[nt][c] = mu;
    ri_s[nt][c] = rsqrtf(var + 1e-5f);
  }
  __syncthreads();
#pragma unroll
  for (int nt = 0; nt < 2; ++nt) {
    float mu = mu_s[nt][l31], ri = ri_s[nt][l31];
    int tg = t0 + ((nt * 32 + l31) >> 3);
    int f = (nt * 32 + l31) & 7;
#pragma unroll
    for (int mt = 0; mt < 2; ++mt) {
#pragma unroll
      for (int r = 0; r < 16; ++r) {
        int row = (r & 3) + 8 * (r >> 2) + 4 * h;
        int o = m0 + mt * 32 + row;
        float v = (acc[mt][nt][r] - mu) * ri * pg[o] + pe[o];
        short bv = bf16_rn(v);
        int head = o >> 6, lo = o & 63;
        int bh = b * 8 + head;
        if (lo < 32) {
          qkb[((size_t)(bh * 32 + lo) * 1024 + tg) * 8 + f] = bv;
        } else {
          vpb[((size_t)(bh * 128 + (tg >> 3)) * 256 + f * 32 + (lo - 32)) * 8 +
              (tg & 7)] = bv;
        }
      }
    }
  }
}

// ---------------- attention: MFMA flash, 4 waves cooperate on 32 queries ---
// grid (x=bh, y=qtile) -> linear id % 8 == bh % 8 -> per-XCD K/V locality.
__global__ __launch_bounds__(256) void attn_mfma(const short* __restrict__ qkb,
                                                 const short* __restrict__ vpb,
                                                 short* __restrict__ ctxb) {
  __shared__ short pbuf[10][64 * 8];  // P A-frags, [frag][lane*8]
  __shared__ float wmax[4][32], wsum[4][32];
  int bh = blockIdx.x;
  int qt0 = blockIdx.y * 32;
  int tid = threadIdx.x;
  int wv = tid >> 6, lane = tid & 63;
  int l31 = lane & 31, h = lane >> 5;
  int b = bh >> 3, hh = bh & 7;
  const short* qbase = qkb + (size_t)bh * 32 * 1024 * 8;
  short8 qf[8];
#pragma unroll
  for (int kk = 0; kk < 8; ++kk) {
    int qc = 2 * kk + h;
    qf[kk] = *(const short8*)(qbase + ((size_t)qc * 1024 + qt0 + l31) * 8);
  }
  int ks_lo = qt0 > 100 ? ((qt0 - 100) & ~31) : 0;
  int kt_n = (qt0 + 32 - ks_lo) >> 5;  // 1..5 (block-uniform)
  int kt0 = wv, kt1 = wv + 4;
  bool has0 = kt0 < kt_n, has1 = kt1 < kt_n;
  int q_t = qt0 + l31;
  f32x16 S0, S1;
  float pm = -INFINITY;
  if (has0) {
#pragma unroll
    for (int r = 0; r < 16; ++r) S0[r] = 0.f;
    int sb = ks_lo + kt0 * 32;
#pragma unroll
    for (int kk = 0; kk < 8; ++kk) {
      int kc = 16 + 2 * kk + h;
      short8 kf = *(const short8*)(qbase + ((size_t)kc * 1024 + sb + l31) * 8);
      S0 = __builtin_amdgcn_mfma_f32_32x32x16_bf16(kf, qf[kk], S0, 0, 0, 0);
    }
#pragma unroll
    for (int r = 0; r < 16; ++r) {
      int s = sb + (r & 3) + 8 * (r >> 2) + 4 * h;
      float v = S0[r] * 0.08838834764831843f;
      bool ok = (s <= q_t) && (s + 100 >= q_t);
      v = ok ? v : -INFINITY;
      S0[r] = v;
      pm = fmaxf(pm, v);
    }
  }
  if (has1) {
#pragma unroll
    for (int r = 0; r < 16; ++r) S1[r] = 0.f;
    int sb = ks_lo + kt1 * 32;
#pragma unroll
    for (int kk = 0; kk < 8; ++kk) {
      int kc = 16 + 2 * kk + h;
      short8 kf = *(const short8*)(qbase + ((size_t)kc * 1024 + sb + l31) * 8);
      S1 = __builtin_amdgcn_mfma_f32_32x32x16_bf16(kf, qf[kk], S1, 0, 0, 0);
    }
#pragma unroll
    for (int r = 0; r < 16; ++r) {
      int s = sb + (r & 3) + 8 * (r >> 2) + 4 * h;
      float v = S1[r] * 0.08838834764831843f;
      bool ok = (s <= q_t) && (s + 100 >= q_t);
      v = ok ? v : -INFINITY;
      S1[r] = v;
      pm = fmaxf(pm, v);
    }
  }
  pm = fmaxf(pm, __shfl_xor(pm, 32, 64));
  if (h == 0) wmax[wv][l31] = pm;
  __syncthreads();
  float gm = fmaxf(fmaxf(wmax[0][l31], wmax[1][l31]),
                   fmaxf(wmax[2][l31], wmax[3][l31]));
  float ws = 0.f;
  if (has0) {
#pragma unroll
    for (int r = 0; r < 16; ++r) {
      float e = __expf(S0[r] - gm);
      S0[r] = e;
      ws += e;
    }
  }
  if (has1) {
#pragma unroll
    for (int r = 0; r < 16; ++r) {
      float e = __expf(S1[r] - gm);
      S1[r] = e;
      ws += e;
    }
  }
  ws += __shfl_xor(ws, 32, 64);
  if (h == 0) wsum[wv][l31] = ws;
  __syncthreads();
  float inv =
      1.f / (wsum[0][l31] + wsum[1][l31] + wsum[2][l31] + wsum[3][l31]);
  if (has0) {
#pragma unroll
    for (int ks2 = 0; ks2 < 2; ++ks2) {
      short tmp8[8];
#pragma unroll
      for (int jj = 0; jj < 4; ++jj) {
        int rA = 8 * ks2 + jj, rB = rA + 4;
        short a16 = bf16_rn(S0[rA] * inv);
        short b16 = bf16_rn(S0[rB] * inv);
        int pk = (int)(unsigned short)a16 | (((int)b16) << 16);
        int xp = __shfl_xor(pk, 32, 64);
        tmp8[jj] = h == 0 ? a16 : (short)(xp >> 16);
        tmp8[4 + jj] = h == 0 ? (short)(xp & 0xffff) : b16;
      }
      *(short8*)&pbuf[kt0 * 2 + ks2][lane * 8] = *(short8*)tmp8;
    }
  }
  if (has1) {
#pragma unroll
    for (int ks2 = 0; ks2 < 2; ++ks2) {
      short tmp8[8];
#pragma unroll
      for (int jj = 0; jj < 4; ++jj) {
        int rA = 8 * ks2 + jj, rB = rA + 4;
        short a16 = bf16_rn(S1[rA] * inv);
        short b16 = bf16_rn(S1[rB] * inv);
        int pk = (int)(unsigned short)a16 | (((int)b16) << 16);
        int xp = __shfl_xor(pk, 32, 64);
        tmp8[jj] = h == 0 ? a16 : (short)(xp >> 16);
        tmp8[4 + jj] = h == 0 ? (short)(xp & 0xffff) : b16;
      }
      *(short8*)&pbuf[kt1 * 2 + ks2][lane * 8] = *(short8*)tmp8;
    }
  }
  __syncthreads();
  const short* vbase = vpb + (size_t)bh * 128 * 256 * 8;
#pragma unroll
  for (int j = 0; j < 2; ++j) {
    int nt = wv * 2 + j;
    f32x16 acc;
#pragma unroll
    for (int r = 0; r < 16; ++r) acc[r] = 0.f;
    for (int kt = 0; kt < kt_n; ++kt) {
#pragma unroll
      for (int ks2 = 0; ks2 < 2; ++ks2) {
        short8 pfr = *(const short8*)&pbuf[kt * 2 + ks2][lane * 8];
        int sb = ks_lo + kt * 32 + ks2 * 16 + h * 8;
        short8 vf = *(const short8*)(vbase +
                                     ((size_t)(sb >> 3) * 256 + nt * 32 + l31) * 8);
        acc = __builtin_amdgcn_mfma_f32_32x32x16_bf16(pfr, vf, acc, 0, 0, 0);
      }
    }
    short* crow = ctxb + ((size_t)(b * 8 + nt) * T_DIM) * 256 + hh * 32 + l31;
#pragma unroll
    for (int r = 0; r < 16; ++r) {
      int t = qt0 + (r & 3) + 8 * (r >> 2) + 4 * h;
      if (t < T_DIM) crow[(size_t)t * 256] = bf16_rn(acc[r]);
    }
  }
}

// ---------------- proj: MFMA GEMM M=256 K=256 Ntile=64, 4 waves ------------
// block id = tb*32 + bf  ->  id % 8 == bf % 8 (per-XCD ctx locality)
__global__ __launch_bounds__(256) void proj_mfma(
    const short* __restrict__ ctxb, const short* __restrict__ wb,
    const float* __restrict__ bias, const float* __restrict__ a_p,
    const float* __restrict__ gam, const float* __restrict__ bet,
    float* __restrict__ out) {
  __shared__ short Bs[64][264];
  __shared__ float lnS[4][2][32], lnQ[4][2][32];
  __shared__ float mu_s[2][32], ri_s[2][32];
  __shared__ float pb[256], pg[256], pe[256];
  int tid = threadIdx.x;
  int blk = blockIdx.x;
  int bf = blk & 31, tb = blk >> 5;
  int b = bf >> 3, f = bf & 7;
  int t0 = tb * 64;
  pb[tid] = bias[tid];
  pg[tid] = gam[tid];
  pe[tid] = bet[tid];
  {
    int row = tid >> 2, seg = (tid & 3) * 64;
    int t = t0 + row;
    if (t < T_DIM) {
      const short8* src =
          (const short8*)(ctxb + ((size_t)bf * T_DIM + t) * 256 + seg);
#pragma unroll
      for (int j = 0; j < 8; ++j) *(short8*)&Bs[row][seg + 8 * j] = src[j];
    } else {
      short8 z = {0, 0, 0, 0, 0, 0, 0, 0};
#pragma unroll
      for (int j = 0; j < 8; ++j) *(short8*)&Bs[row][seg + 8 * j] = z;
    }
  }
  __syncthreads();
  int lane = tid & 63, wv = tid >> 6;
  int h = lane >> 5, l31 = lane & 31;
  int m0 = wv * 64;
  f32x16 acc[2][2];
#pragma unroll
  for (int mt = 0; mt < 2; ++mt)
#pragma unroll
    for (int nt = 0; nt < 2; ++nt)
#pragma unroll
      for (int r = 0; r < 16; ++r) acc[mt][nt][r] = 0.f;
  const short* wbase = wb + ((size_t)(m0 + l31)) * 256 + h * 8;
#pragma unroll
  for (int kk = 0; kk < 16; ++kk) {
    short8 bfr0 = *(const short8*)&Bs[l31][kk * 16 + h * 8];
    short8 bfr1 = *(const short8*)&Bs[32 + l31][kk * 16 + h * 8];
#pragma unroll
    for (int mt = 0; mt < 2; ++mt) {
      short8 af = *(const short8*)(wbase + (size_t)mt * 32 * 256 + kk * 16);
      acc[mt][0] =
          __builtin_amdgcn_mfma_f32_32x32x16_bf16(af, bfr0, acc[mt][0], 0, 0, 0);
      acc[mt][1] =
          __builtin_amdgcn_mfma_f32_32x32x16_bf16(af, bfr1, acc[mt][1], 0, 0, 0);
    }
  }
  float aslope = a_p[0];
  float sm[2] = {0.f, 0.f}, sq[2] = {0.f, 0.f};
#pragma unroll
  for (int mt = 0; mt < 2; ++mt) {
#pragma unroll
    for (int nt = 0; nt < 2; ++nt) {
#pragma unroll
      for (int r = 0; r < 16; ++r) {
        int row = (r & 3) + 8 * (r >> 2) + 4 * h;
        int o = m0 + mt * 32 + row;
        float v = acc[mt][nt][r] + pb[o];
        v = v >= 0.f ? v : aslope * v;
        acc[mt][nt][r] = v;
        sm[nt] += v;
        sq[nt] += v * v;
      }
    }
  }
#pragma unroll
  for (int nt = 0; nt < 2; ++nt) {
    sm[nt] += __shfl_xor(sm[nt], 32, 64);
    sq[nt] += __shfl_xor(sq[nt], 32, 64);
    if (h == 0) {
      lnS[wv][nt][l31] = sm[nt];
      lnQ[wv][nt][l31] = sq[nt];
    }
  }
  __syncthreads();
  if (tid < 64) {
    int nt = tid >> 5, c = tid & 31;
    float ss = lnS[0][nt][c] + lnS[1][nt][c] + lnS[2][nt][c] + lnS[3][nt][c];
    float qq = lnQ[0][nt][c] + lnQ[1][nt][c] + lnQ[2][nt][c] + lnQ[3][nt][c];
    float mu = ss * (1.f / 256.f);
    float var = qq * (1.f / 256.f) - mu * mu;
    mu_s[nt][c] = mu;
    ri_s[nt][c] = rsqrtf(var + 1e-5f);
  }
  __syncthreads();
#pragma unroll
  for (int nt = 0; nt < 2; ++nt) {
    float mu = mu_s[nt][l31], ri = ri_s[nt][l31];
    int t = t0 + nt * 32 + l31;
    if (t < T_DIM) {
#pragma unroll
      for (int mt = 0; mt < 2; ++mt) {
#pragma unroll
        for (int r = 0; r < 16; ++r) {
          int row = (r & 3) + 8 * (r >> 2) + 4 * h;
          int o = m0 + mt * 32 + row;
          float v = (acc[mt][nt][r] - mu) * ri * pg[o] + pe[o];
          out[((size_t)(b * 2048 + o * 8 + f)) * T_DIM + t] = v;
        }
      }
    }
  }
}

extern "C" void kernel_launch(void* const* d_in, const int* in_sizes, int n_in,
                              void* d_out, int out_size, void* d_ws,
                              size_t ws_size, hipStream_t stream) {
  const float* x = (const float*)d_in[0];
  const float* w_qkv = (const float*)d_in[1];
  const float* b_qkv = (const float*)d_in[2];
  const float* a_qkv = (const float*)d_in[3];
  const float* g_qkv = (const float*)d_in[4];
  const float* be_qkv = (const float*)d_in[5];
  const float* w_proj = (const float*)d_in[6];
  const float* b_proj = (const float*)d_in[7];
  const float* a_proj = (const float*)d_in[8];
  const float* g_proj = (const float*)d_in[9];
  const float* be_proj = (const float*)d_in[10];
  float* out = (float*)d_out;

  short* wqb = (short*)d_ws;            // 512*256
  short* wpb = wqb + 131072;            // 256*256
  short* qkb = wpb + 65536;             // 32*32*1024*8
  short* vpb = qkb + (size_t)8388608;   // 32*128*256*8
  short* ctxb = vpb + (size_t)8388608;  // 32000*256

  prep_w<<<768, 256, 0, stream>>>(w_qkv, w_proj, wqb, wpb);
  qkv_mfma<<<500, 512, 0, stream>>>(x, wqb, b_qkv, a_qkv, g_qkv, be_qkv,
                                    qkb, vpb);
  attn_mfma<<<dim3(32, 32), 256, 0, stream>>>(qkb, vpb, ctxb);
  proj_mfma<<<512, 256, 0, stream>>>(ctxb, wpb, b_proj, a_proj, g_proj,
                                     be_proj, out);
}